// Round 14
// baseline (256.609 us; speedup 1.0000x reference)
//
#include <hip/hip_runtime.h>
#include <hip/hip_bf16.h>
#include <stdint.h>

typedef __attribute__((ext_vector_type(8))) short s16x8;
typedef __attribute__((ext_vector_type(4))) float f32x4;

#define DEVFN static __device__ __forceinline__

DEVFN unsigned short f2bf(float f) {
    union { float f; uint32_t u; } v; v.f = f;
    uint32_t u = v.u;
    uint32_t r = (u + 0x7fffu + ((u >> 16) & 1u)) >> 16;
    return (unsigned short)r;
}
DEVFN float bf2f(unsigned short h) {
    union { uint32_t u; float f; } v; v.u = ((uint32_t)h) << 16;
    return v.f;
}
DEVFN float bfu_lo(uint32_t v) {
    union { uint32_t u; float f; } c; c.u = v << 16; return c.f;
}
DEVFN float bfu_hi(uint32_t v) {
    union { uint32_t u; float f; } c; c.u = v & 0xffff0000u; return c.f;
}
DEVFN uint32_t cvtpk(float lo, float hi) {
    uint32_t r;
    asm("v_cvt_pk_bf16_f32 %0, %1, %2" : "=v"(r) : "v"(lo), "v"(hi));
    return r;
}

DEVFN void gload16(const void* g, void* l) {
    __builtin_amdgcn_global_load_lds(
        (const __attribute__((address_space(1))) unsigned int*)(uintptr_t)g,
        (__attribute__((address_space(3))) unsigned int*)(uint32_t)(uintptr_t)l,
        16, 0, 0);
}

DEVFN f32x4 mfma16(s16x8 a, s16x8 b, f32x4 c) {
    return __builtin_amdgcn_mfma_f32_16x16x32_bf16(a, b, c, 0, 0, 0);
}

// swizzled fragment read: tile rows are 128 B; XOR row-bits into 16B-slot bits
DEVFN s16x8 ldfrag(const unsigned short* base, int row, int cb) {
    return *(const s16x8*)((const char*)base + row * 128 + (cb ^ ((row & 7) << 4)));
}

// ---------------------------------------------------------------- converts
__global__ __launch_bounds__(256) void k_convert_cat(const float* __restrict__ mems,
                                                     const float* __restrict__ w,
                                                     unsigned short* __restrict__ catb) {
    const long long total4 = 2097152;  // 8M elems / 4
    for (long long i = (long long)blockIdx.x * blockDim.x + threadIdx.x; i < total4;
         i += (long long)gridDim.x * blockDim.x) {
        float4 v = (i < 1048576) ? ((const float4*)mems)[i] : ((const float4*)w)[i - 1048576];
        ushort4 o = make_ushort4(f2bf(v.x), f2bf(v.y), f2bf(v.z), f2bf(v.w));
        ((ushort4*)catb)[i] = o;
    }
}

// in fp32 [R][C] -> out bf16 [C][R]
__global__ __launch_bounds__(256) void k_transpose_convert(const float* __restrict__ in,
                                                           unsigned short* __restrict__ out,
                                                           int R, int C) {
    __shared__ float T[32][33];
    int c0 = blockIdx.x * 32, r0 = blockIdx.y * 32;
    int tx = threadIdx.x, ty = threadIdx.y;  // (32,8)
#pragma unroll
    for (int i = 0; i < 4; ++i) {
        int r = ty * 4 + i;
        T[r][tx] = in[(size_t)(r0 + r) * C + c0 + tx];
    }
    __syncthreads();
#pragma unroll
    for (int i = 0; i < 4; ++i) {
        int r = ty * 4 + i;
        out[(size_t)(c0 + r) * R + r0 + tx] = f2bf(T[tx][r]);
    }
}

// r_emb (2048,16,64) fp32 -> rb [n][jj][d] bf16 ; also r_bias (2048,16) -> rbt [n][jj] f32
__global__ __launch_bounds__(256) void k_remap_remb(const float* __restrict__ r_emb,
                                                    const float* __restrict__ r_bias,
                                                    unsigned short* __restrict__ rb,
                                                    float* __restrict__ rbt) {
    const long long total = 2097152;
    long long tid0 = (long long)blockIdx.x * blockDim.x + threadIdx.x;
    long long stride = (long long)gridDim.x * blockDim.x;
    for (long long o = tid0; o < total; o += stride) {
        int n = (int)(o >> 17);
        int jj = (int)((o >> 6) & 2047);
        int d = (int)(o & 63);
        rb[o] = f2bf(r_emb[((size_t)jj * 16 + n) * 64 + d]);
    }
    for (long long o = tid0; o < 32768; o += stride)
        rbt[o] = r_bias[(size_t)(o & 2047) * 16 + (o >> 11)];
}

// vb [bn][j][d] -> vt [bn][d][j]  (bf16, 64x64 tiles)
__global__ __launch_bounds__(256) void k_vtrans(const unsigned short* __restrict__ vb,
                                                unsigned short* __restrict__ vt) {
    __shared__ unsigned short T[64][72];
    int bn = blockIdx.y;
    int j0 = blockIdx.x * 64;
    int tid = threadIdx.x;
    int r = tid >> 2, cq = (tid & 3) * 16;
    size_t base = (size_t)bn * 131072;
    const unsigned short* src = vb + base + (size_t)(j0 + r) * 64 + cq;
    *(s16x8*)&T[r][cq] = *(const s16x8*)src;
    *(s16x8*)&T[r][cq + 8] = *(const s16x8*)(src + 8);
    __syncthreads();
    int d = r, jq = cq;
    s16x8 o0, o1;
#pragma unroll
    for (int t = 0; t < 8; ++t) { o0[t] = (short)T[jq + t][d]; o1[t] = (short)T[jq + 8 + t][d]; }
    unsigned short* dst = vt + base + (size_t)d * 2048 + j0 + jq;
    *(s16x8*)dst = o0;
    *(s16x8*)(dst + 8) = o1;
}

// ---------------------------------------------------------------- GEMM1 (QKV)
// 1D grid of 1280 blocks; XCD-chunked swizzle (1280 = 8*160, bijective);
// dead-tile remap (mem-row Q tiles skipped).
__global__ __launch_bounds__(256) void k_gemm_qkv(const unsigned short* __restrict__ A,
                                                  const unsigned short* __restrict__ B,
                                                  unsigned short* __restrict__ qb,
                                                  unsigned short* __restrict__ kb,
                                                  unsigned short* __restrict__ vb) {
    __shared__ unsigned short As[128 * 64];
    __shared__ unsigned short Bs[128 * 64];
    const int K = 1024;
    int tid = threadIdx.x, lane = tid & 63, wid = tid >> 6;
    int l15 = lane & 15, l16 = lane >> 4;
    int lbid = ((int)blockIdx.x & 7) * 160 + ((int)blockIdx.x >> 3);  // XCD chunk
    int m0, n0;
    if (lbid < 1024) {
        m0 = (lbid >> 4) * 128;
        n0 = (8 + (lbid & 15)) * 128;
    } else {
        int q = lbid - 1024;
        m0 = (32 + (q >> 3)) * 128;
        n0 = (q & 7) * 128;
    }
    int wr = wid >> 1, wc = wid & 1;
    f32x4 acc[4][4];
#pragma unroll
    for (int a = 0; a < 4; ++a)
#pragma unroll
        for (int b = 0; b < 4; ++b) acc[a][b] = f32x4{0.f, 0.f, 0.f, 0.f};

    for (int k0 = 0; k0 < K; k0 += 64) {
        __syncthreads();
#pragma unroll
        for (int it = 0; it < 4; ++it) {
            int slot = it * 4 + wid;
            int elem = slot * 512 + lane * 8;
            int row = elem >> 6;
            int colb = (lane & 7) * 16;
            int scol = (colb ^ ((row & 7) << 4)) >> 1;
            gload16(A + (size_t)(m0 + row) * K + k0 + scol, (char*)As + (size_t)slot * 1024);
            gload16(B + (size_t)(n0 + row) * K + k0 + scol, (char*)Bs + (size_t)slot * 1024);
        }
        asm volatile("s_waitcnt vmcnt(0)" ::: "memory");
        __syncthreads();
#pragma unroll
        for (int kc = 0; kc < 2; ++kc) {
            s16x8 af[4], bfr[4];
#pragma unroll
            for (int f = 0; f < 4; ++f)
                af[f] = ldfrag(As, wr * 64 + f * 16 + l15, kc * 64 + l16 * 16);
#pragma unroll
            for (int f = 0; f < 4; ++f)
                bfr[f] = ldfrag(Bs, wc * 64 + f * 16 + l15, kc * 64 + l16 * 16);
#pragma unroll
            for (int fm = 0; fm < 4; ++fm)
#pragma unroll
                for (int fn = 0; fn < 4; ++fn)
                    acc[fm][fn] = mfma16(af[fm], bfr[fn], acc[fm][fn]);
        }
    }
#pragma unroll
    for (int fm = 0; fm < 4; ++fm)
#pragma unroll
        for (int fn = 0; fn < 4; ++fn)
#pragma unroll
            for (int r = 0; r < 4; ++r) {
                int row = m0 + wr * 64 + fm * 16 + l16 * 4 + r;
                int col = n0 + wc * 64 + fn * 16 + l15;
                float v = acc[fm][fn][r];
                int t = row >> 2, bb = row & 3;
                if (col < 1024) {
                    if (t >= 1024) {
                        int nn = col >> 6, d = col & 63;
                        qb[((size_t)(bb * 16 + nn) * 1024 + (t - 1024)) * 64 + d] = f2bf(v);
                    }
                } else if (col < 2048) {
                    int c2 = col - 1024, nn = c2 >> 6, d = c2 & 63;
                    kb[((size_t)(bb * 16 + nn) * 2048 + t) * 64 + d] = f2bf(v);
                } else {
                    int c2 = col - 2048, nn = c2 >> 6, d = c2 & 63;
                    vb[((size_t)(bb * 16 + nn) * 2048 + t) * 64 + d] = f2bf(v);
                }
            }
}

// ---------------------------------------------------------------- GEMM2 (out proj + residual)
__global__ __launch_bounds__(256) void k_gemm_out(const unsigned short* __restrict__ A,
                                                  const unsigned short* __restrict__ B,
                                                  const float* __restrict__ wres,
                                                  float* __restrict__ outf) {
    __shared__ unsigned short As[64 * 64];    // 8 KB
    __shared__ unsigned short Bs[128 * 64];   // 16 KB
    const int K = 1024, N = 1024;
    int tid = threadIdx.x, lane = tid & 63, wid = tid >> 6;
    int l15 = lane & 15, l16 = lane >> 4;
    int m0 = blockIdx.y * 64, n0 = blockIdx.x * 128;
    int wr = wid >> 1, wc = wid & 1;
    f32x4 acc[2][4];
#pragma unroll
    for (int a = 0; a < 2; ++a)
#pragma unroll
        for (int b = 0; b < 4; ++b) acc[a][b] = f32x4{0.f, 0.f, 0.f, 0.f};

    for (int k0 = 0; k0 < K; k0 += 64) {
        __syncthreads();
#pragma unroll
        for (int it = 0; it < 6; ++it) {
            int slot = it * 4 + wid;  // 0..23 ; 0-7 -> As, 8-23 -> Bs
            int colb = (lane & 7) * 16;
            if (slot < 8) {
                int elem = slot * 512 + lane * 8;
                int row = elem >> 6;
                int scol = (colb ^ ((row & 7) << 4)) >> 1;
                gload16(A + (size_t)(m0 + row) * K + k0 + scol, (char*)As + (size_t)slot * 1024);
            } else {
                int s2 = slot - 8;
                int elem = s2 * 512 + lane * 8;
                int row = elem >> 6;
                int scol = (colb ^ ((row & 7) << 4)) >> 1;
                gload16(B + (size_t)(n0 + row) * K + k0 + scol, (char*)Bs + (size_t)s2 * 1024);
            }
        }
        asm volatile("s_waitcnt vmcnt(0)" ::: "memory");
        __syncthreads();
#pragma unroll
        for (int kc = 0; kc < 2; ++kc) {
            s16x8 af[2], bfr[4];
#pragma unroll
            for (int f = 0; f < 2; ++f)
                af[f] = ldfrag(As, wr * 32 + f * 16 + l15, kc * 64 + l16 * 16);
#pragma unroll
            for (int f = 0; f < 4; ++f)
                bfr[f] = ldfrag(Bs, wc * 64 + f * 16 + l15, kc * 64 + l16 * 16);
#pragma unroll
            for (int fm = 0; fm < 2; ++fm)
#pragma unroll
                for (int fn = 0; fn < 4; ++fn)
                    acc[fm][fn] = mfma16(af[fm], bfr[fn], acc[fm][fn]);
        }
    }
#pragma unroll
    for (int fm = 0; fm < 2; ++fm)
#pragma unroll
        for (int fn = 0; fn < 4; ++fn)
#pragma unroll
            for (int r = 0; r < 4; ++r) {
                int row = m0 + wr * 32 + fm * 16 + l16 * 4 + r;
                int col = n0 + wc * 64 + fn * 16 + l15;
                size_t o = (size_t)row * N + col;
                outf[o] = acc[fm][fn][r] + wres[o];
            }
}

// ---------------------------------------------------------------- attention
// r13 structure + VALU strength-reduction: all LDS fragment addresses hoisted
// to per-lane iter-invariant byte offsets (offKV shared by AC/PV; R-ring
// offsets wrapped by single conditional subtract); prefetch uses running
// pointers and issues at LOOP TOP (full-iteration latency cover).
__global__ __launch_bounds__(256) void k_attn(const unsigned short* __restrict__ qb,
                                              const unsigned short* __restrict__ kb,
                                              const unsigned short* __restrict__ vt,
                                              const unsigned short* __restrict__ rb,
                                              const float* __restrict__ rbt,
                                              const float* __restrict__ r_w_bias,
                                              unsigned short* __restrict__ av) {
    __shared__ unsigned short Ks[2][4096];   // [buf][jf][d] swizzled   16 KB
    __shared__ unsigned short Vs[2][4096];   // [buf][d][jf] swizzled   16 KB
    __shared__ unsigned short Rs[192 * 64];  // tri-buffer, swizzled    24 KB
    __shared__ unsigned short Elp[4][1920];  // El pool (Ps aliased)    15 KB
    __shared__ float rbs[192];               // tri-buffer band bias   .75 KB

    const float SC = 0.18033688f;  // 0.125 * log2(e)
    int tid = threadIdx.x, lane = tid & 63, wid = tid >> 6;
    int l15 = lane & 15, l16 = lane >> 4;
    int qr0 = l16 * 4;
    int bn = blockIdx.y, b = bn >> 4, n = bn & 15;
    size_t bq = (size_t)bn * 65536;
    size_t bk = (size_t)bn * 131072;
    const unsigned short* rbn = rb + (size_t)n * 131072;
    int rbase = 48 - wid * 16;              // wave band-window start offset
    int lrow = lane >> 3;                   // dest row within an 8-row group
    int colb = (lane & 7) * 16;             // dest byte col
    int scolE = (colb ^ (lrow << 4)) >> 1;  // swizzled source col (elements)

    // ---- hoisted per-lane LDS byte offsets (iter-invariant) ----
    const char* KsB = (const char*)&Ks[0][0];
    const char* VsB = (const char*)&Vs[0][0];
    const char* RsB = (const char*)&Rs[0];
    int offKV[2][4];  // AC(Ks) and PV(Vs) share geometry: row=f*16+l15, cb=kc*64+l16*16
#pragma unroll
    for (int f = 0; f < 4; ++f) {
        int row = f * 16 + l15;
        int swz = (row & 7) << 4;
#pragma unroll
        for (int kc = 0; kc < 2; ++kc)
            offKV[kc][f] = row * 128 + ((kc * 64 + l16 * 16) ^ swz);
    }
    int offE[2][5], offRb[5];  // R-ring: add rsb*128 (rsb%8==0 so swz invariant)
#pragma unroll
    for (int fe = 0; fe < 5; ++fe) {
        int row0 = rbase + fe * 16 + l15;  // in [0,128)
        int swz = (row0 & 7) << 4;
        offE[0][fe] = row0 * 128 + ((l16 * 16) ^ swz);
        offE[1][fe] = row0 * 128 + ((64 + l16 * 16) ^ swz);
        offRb[fe] = row0 * 4;
    }

    // loop-invariant El/Ps addresses (offsets are immediates)
    unsigned short* ElW = &Elp[wid][20 * l15 + 21 * qr0];          // + fe*320 + r*21
    const unsigned short* ElR = &Elp[wid][20 * (l15 + 15) + qr0];  // + fn*320, b64
    unsigned short* PsW = &Elp[wid][qr0 * 68 + l15];               // + fn*16 + r*68
    const unsigned short* PsR = &Elp[wid][l15 * 68];               // + kc*32 + l16*8

    s16x8 ones;
#pragma unroll
    for (int t = 0; t < 8; ++t) ones[t] = (short)0x3F80;  // bf16 1.0

    for (int h = 0; h < 2; ++h) {
        int it8 = h ? 15 - (int)blockIdx.x : (int)blockIdx.x;
        int i0 = it8 * 64;
        int njt = it8 + 17;
        int jjb = 960 - i0;  // band base

        // Q fragments (pre-scaled by SC)
        s16x8 aq[2], aqr[2];
        {
            int qrow = i0 + wid * 16 + l15;
#pragma unroll
            for (int kc = 0; kc < 2; ++kc) {
                s16x8 qv = *(const s16x8*)(qb + bq + (size_t)qrow * 64 + kc * 32 + l16 * 8);
                s16x8 q1, q2;
#pragma unroll
                for (int t = 0; t < 8; ++t) {
                    float f = bf2f((unsigned short)qv[t]);
                    float rw = r_w_bias[n * 64 + kc * 32 + l16 * 8 + t];
                    q1[t] = (short)f2bf(f * SC);
                    q2[t] = (short)f2bf((f + rw) * SC);
                }
                aq[kc] = q1;
                aqr[kc] = q2;
            }
        }

        float m_[4];
        f32x4 accO[4], accL;
#pragma unroll
        for (int r = 0; r < 4; ++r) m_[r] = -3.0e38f;
#pragma unroll
        for (int f = 0; f < 4; ++f) accO[f] = f32x4{0.f, 0.f, 0.f, 0.f};
        accL = f32x4{0.f, 0.f, 0.f, 0.f};

        // ---- prologue: K/V tile 0, R band rows [0,128), rbs ----
#pragma unroll
        for (int q = 0; q < 2; ++q) {
            int s = wid * 2 + q;
            int row = s * 8 + lrow;
            gload16(kb + bk + (size_t)row * 64 + scolE, (char*)Ks[0] + s * 1024);
            gload16(vt + bk + (size_t)row * 2048 + scolE, (char*)Vs[0] + s * 1024);
        }
#pragma unroll
        for (int q = 0; q < 4; ++q) {
            int s = wid * 4 + q;
            int jju = jjb + s * 8 + lrow;
            gload16(rbn + (size_t)jju * 64 + scolE, (char*)Rs + (s * 8) * 128);
        }
        if (tid < 128) {
            int jju = jjb + tid;
            rbs[tid] = SC * rbt[(size_t)n * 2048 + jju];
        }
        __syncthreads();

        // running prefetch pointers (start at tile 1)
        const unsigned short* kp0 = kb + bk + (size_t)(64 + wid * 16 + lrow) * 64 + scolE;
        const unsigned short* kp1 = kb + bk + (size_t)(64 + wid * 16 + 8 + lrow) * 64 + scolE;
        const unsigned short* vp0 = vt + bk + (size_t)(wid * 16 + lrow) * 2048 + 64 + scolE;
        const unsigned short* vp1 = vt + bk + (size_t)(wid * 16 + 8 + lrow) * 2048 + 64 + scolE;
        int jjp0 = jjb + 128 + wid * 16 + lrow;
        int jjp1 = jjb + 128 + wid * 16 + 8 + lrow;

        int curK = 0, rsb = 0;  // curK: byte offset of active K/V buffer; rsb: ring row base
        for (int jt = 0; jt < njt; ++jt) {
            int jjc = jjb + jt * 64;
            bool pf = (jt + 1 < njt);

            // ---- prefetch issue at loop top (full-iter latency cover) ----
            if (pf) {
                int nxt = curK ^ 8192;
                gload16(kp0, (char*)KsB + nxt + (wid * 2) * 1024);
                gload16(kp1, (char*)KsB + nxt + (wid * 2 + 1) * 1024);
                gload16(vp0, (char*)VsB + nxt + (wid * 2) * 1024);
                gload16(vp1, (char*)VsB + nxt + (wid * 2 + 1) * 1024);
                kp0 += 4096; kp1 += 4096; vp0 += 64; vp1 += 64;
                int w0 = rsb + 128 + wid * 16;
                if (w0 >= 192) w0 -= 192;
                int w1 = rsb + 136 + wid * 16;
                if (w1 >= 192) w1 -= 192;
                int ja0 = jjp0 > 2047 ? 2047 : jjp0;
                int ja1 = jjp1 > 2047 ? 2047 : jjp1;
                gload16(rbn + (size_t)ja0 * 64 + scolE, (char*)RsB + w0 * 128);
                gload16(rbn + (size_t)ja1 * 64 + scolE, (char*)RsB + w1 * 128);
                jjp0 += 64; jjp1 += 64;
                if (tid < 64) {
                    int w2 = rsb + 128 + tid;
                    if (w2 >= 192) w2 -= 192;
                    int jju = jjc + 128 + tid;
                    rbs[w2] = (jju <= 2047) ? SC * rbt[(size_t)n * 2048 + jju] : -1.0e30f;
                }
            }

            int rsbB = rsb * 128, rsbF = rsb * 4;
            // E = q . R_window^T -> skewed El, rbias+mask folded
            __builtin_amdgcn_s_setprio(1);
#pragma unroll
            for (int fe = 0; fe < 5; ++fe) {
                int e0 = offE[0][fe] + rsbB;
                if (e0 >= 24576) e0 -= 24576;
                int e1 = offE[1][fe] + rsbB;
                if (e1 >= 24576) e1 -= 24576;
                f32x4 e = f32x4{0.f, 0.f, 0.f, 0.f};
                e = mfma16(aq[0], *(const s16x8*)(RsB + e0), e);
                e = mfma16(aq[1], *(const s16x8*)(RsB + e1), e);
                int er = offRb[fe] + rsbF;
                if (er >= 768) er -= 768;
                float rbv = *(const float*)((const char*)rbs + er);
                uint32_t p01 = cvtpk(e[0] + rbv, e[1] + rbv);
                uint32_t p23 = cvtpk(e[2] + rbv, e[3] + rbv);
                ElW[fe * 320] = (unsigned short)p01;
                ElW[fe * 320 + 21] = (unsigned short)(p01 >> 16);
                ElW[fe * 320 + 42] = (unsigned short)p23;
                ElW[fe * 320 + 63] = (unsigned short)(p23 >> 16);
            }
            // AC = (q + r_w_bias) . K^T
            f32x4 sAC[4];
#pragma unroll
            for (int fn = 0; fn < 4; ++fn) {
                f32x4 a = f32x4{0.f, 0.f, 0.f, 0.f};
                a = mfma16(aqr[0], *(const s16x8*)(KsB + curK + offKV[0][fn]), a);
                a = mfma16(aqr[1], *(const s16x8*)(KsB + curK + offKV[1][fn]), a);
                sAC[fn] = a;
            }
            __builtin_amdgcn_s_setprio(0);

            // softmax: scores via 4x b64 diagonal reads; defer-max THR=8
            float pe[4][4];
            float lmax[4] = {-3.0e38f, -3.0e38f, -3.0e38f, -3.0e38f};
#pragma unroll
            for (int fn = 0; fn < 4; ++fn) {
                uint2 ev = *(const uint2*)(ElR + fn * 320);
                pe[fn][0] = sAC[fn][0] + bfu_lo(ev.x);
                pe[fn][1] = sAC[fn][1] + bfu_hi(ev.x);
                pe[fn][2] = sAC[fn][2] + bfu_lo(ev.y);
                pe[fn][3] = sAC[fn][3] + bfu_hi(ev.y);
#pragma unroll
                for (int r = 0; r < 4; ++r) lmax[r] = fmaxf(lmax[r], pe[fn][r]);
            }
            bool need = (lmax[0] > m_[0] + 8.f) | (lmax[1] > m_[1] + 8.f) |
                        (lmax[2] > m_[2] + 8.f) | (lmax[3] > m_[3] + 8.f);
            if (__any(need)) {
#pragma unroll
                for (int msk = 1; msk <= 8; msk <<= 1)
#pragma unroll
                    for (int r = 0; r < 4; ++r)
                        lmax[r] = fmaxf(lmax[r], __shfl_xor(lmax[r], msk, 64));
#pragma unroll
                for (int r = 0; r < 4; ++r) {
                    float mn = fmaxf(m_[r], lmax[r]);
                    float alpha = __builtin_exp2f(m_[r] - mn);
                    m_[r] = mn;
                    accL[r] *= alpha;
#pragma unroll
                    for (int f = 0; f < 4; ++f) accO[f][r] *= alpha;
                }
            }
            // all El reads above complete before these aliased Ps writes
#pragma unroll
            for (int fn = 0; fn < 4; ++fn) {
                float e0 = __builtin_exp2f(pe[fn][0] - m_[0]);
                float e1 = __builtin_exp2f(pe[fn][1] - m_[1]);
                float e2 = __builtin_exp2f(pe[fn][2] - m_[2]);
                float e3 = __builtin_exp2f(pe[fn][3] - m_[3]);
                uint32_t a = cvtpk(e0, e1);
                uint32_t c = cvtpk(e2, e3);
                PsW[fn * 16] = (unsigned short)a;
                PsW[fn * 16 + 68] = (unsigned short)(a >> 16);
                PsW[fn * 16 + 136] = (unsigned short)c;
                PsW[fn * 16 + 204] = (unsigned short)(c >> 16);
            }

            // PV (+ row-sum via ones-MFMA); Ps rows 8B-aligned -> 2x b64
            __builtin_amdgcn_s_setprio(1);
#pragma unroll
            for (int kc = 0; kc < 2; ++kc) {
                const uint2* pp = (const uint2*)(PsR + kc * 32 + l16 * 8);
                union { uint2 u2[2]; s16x8 v; } uu;
                uu.u2[0] = pp[0];
                uu.u2[1] = pp[1];
                s16x8 pa = uu.v;
                accL = mfma16(pa, ones, accL);
#pragma unroll
                for (int fd = 0; fd < 4; ++fd)
                    accO[fd] = mfma16(pa, *(const s16x8*)(VsB + curK + offKV[kc][fd]),
                                      accO[fd]);
            }
            __builtin_amdgcn_s_setprio(0);

            __syncthreads();  // single barrier: drains prefetch, publishes all buffers
            curK ^= 8192;
            rsb += 64;
            if (rsb == 192) rsb = 0;
        }

        // write attn_vec row-normalized, bf16, layout [i*4+b][n*64+d]
#pragma unroll
        for (int r = 0; r < 4; ++r) {
            float inv = 1.f / accL[r];
            int ig = i0 + wid * 16 + qr0 + r;
#pragma unroll
            for (int fd = 0; fd < 4; ++fd)
                av[((size_t)ig * 4 + b) * 1024 + n * 64 + fd * 16 + l15] = f2bf(accO[fd][r] * inv);
        }
    }
}

// ---------------------------------------------------------------- layernorm (in-place on d_out)
__global__ __launch_bounds__(256) void k_ln(float* __restrict__ y, const float* __restrict__ g,
                                            const float* __restrict__ bta) {
    int row = blockIdx.x, tid = threadIdx.x;
    int lane = tid & 63, wid = tid >> 6;
    float4 v = ((const float4*)(y + (size_t)row * 1024))[tid];
    float s = v.x + v.y + v.z + v.w;
    float sq = v.x * v.x + v.y * v.y + v.z * v.z + v.w * v.w;
#pragma unroll
    for (int msk = 1; msk <= 32; msk <<= 1) {
        s += __shfl_xor(s, msk, 64);
        sq += __shfl_xor(sq, msk, 64);
    }
    __shared__ float red[2][4];
    if (lane == 0) { red[0][wid] = s; red[1][wid] = sq; }
    __syncthreads();
    s = red[0][0] + red[0][1] + red[0][2] + red[0][3];
    sq = red[1][0] + red[1][1] + red[1][2] + red[1][3];
    float mu = s * (1.f / 1024.f);
    float var = sq * (1.f / 1024.f) - mu * mu;
    float rs = rsqrtf(var + 1e-5f);
    float4 gv = ((const float4*)g)[tid];
    float4 bv = ((const float4*)bta)[tid];
    float4 o;
    o.x = (v.x - mu) * rs * gv.x + bv.x;
    o.y = (v.y - mu) * rs * gv.y + bv.y;
    o.z = (v.z - mu) * rs * gv.z + bv.z;
    o.w = (v.w - mu) * rs * gv.w + bv.w;
    ((float4*)(y + (size_t)row * 1024))[tid] = o;
}

// ---------------------------------------------------------------- launch
extern "C" void kernel_launch(void* const* d_in, const int* in_sizes, int n_in,
                              void* d_out, int out_size, void* d_ws, size_t ws_size,
                              hipStream_t stream) {
    const float* w      = (const float*)d_in[0];
    const float* mems   = (const float*)d_in[1];
    const float* r_emb  = (const float*)d_in[2];
    const float* r_wb   = (const float*)d_in[3];
    const float* r_bias = (const float*)d_in[4];
    const float* Wqkv   = (const float*)d_in[5];
    const float* Wo     = (const float*)d_in[6];
    const float* ln_g   = (const float*)d_in[7];
    const float* ln_b   = (const float*)d_in[8];
    float* out = (float*)d_out;

    char* p = (char*)d_ws;
    auto alloc = [&](size_t bytes) {
        char* q = p;
        p += (bytes + 255) & ~(size_t)255;
        return q;
    };
    unsigned short* catb  = (unsigned short*)alloc(8192ull * 1024 * 2);      // 16 MB
    unsigned short* wqkvT = (unsigned short*)alloc(3072ull * 1024 * 2);      // 6 MB
    unsigned short* woT   = (unsigned short*)alloc(1024ull * 1024 * 2);      // 2 MB
    unsigned short* rb    = (unsigned short*)alloc(16ull * 2048 * 64 * 2);   // 4 MB
    float*          rbt   = (float*)alloc(16ull * 2048 * 4);                 // 128 KB
    unsigned short* qbuf  = (unsigned short*)alloc(64ull * 1024 * 64 * 2);   // 8 MB
    unsigned short* kbuf  = (unsigned short*)alloc(64ull * 2048 * 64 * 2);   // 16 MB
    unsigned short* vbuf  = (unsigned short*)alloc(64ull * 2048 * 64 * 2);   // 16 MB
    unsigned short* av    = (unsigned short*)alloc(4096ull * 1024 * 2);      // 8 MB
    unsigned short* vtb = catb;  // catb dead after GEMM1

    k_convert_cat<<<2048, 256, 0, stream>>>(mems, w, catb);
    dim3 tb(32, 8);
    k_transpose_convert<<<dim3(96, 32), tb, 0, stream>>>(Wqkv, wqkvT, 1024, 3072);
    k_transpose_convert<<<dim3(32, 32), tb, 0, stream>>>(Wo, woT, 1024, 1024);
    k_remap_remb<<<2048, 256, 0, stream>>>(r_emb, r_bias, rb, rbt);

    k_gemm_qkv<<<1280, 256, 0, stream>>>(catb, wqkvT, qbuf, kbuf, vbuf);
    k_vtrans<<<dim3(32, 64), 256, 0, stream>>>(vbuf, vtb);
    k_attn<<<dim3(8, 64), 256, 0, stream>>>(qbuf, kbuf, vtb, rb, rbt, r_wb, av);
    k_gemm_out<<<dim3(8, 64), 256, 0, stream>>>(av, woT, w, out);
    k_ln<<<4096, 256, 0, stream>>>(out, ln_g, ln_b);
}

// Round 15
// 239.881 us; speedup vs baseline: 1.0697x; 1.0697x over previous
//
#include <hip/hip_runtime.h>
#include <hip/hip_bf16.h>
#include <stdint.h>

typedef __attribute__((ext_vector_type(8))) short s16x8;
typedef __attribute__((ext_vector_type(4))) float f32x4;

#define DEVFN static __device__ __forceinline__

DEVFN unsigned short f2bf(float f) {
    union { float f; uint32_t u; } v; v.f = f;
    uint32_t u = v.u;
    uint32_t r = (u + 0x7fffu + ((u >> 16) & 1u)) >> 16;
    return (unsigned short)r;
}
DEVFN float bf2f(unsigned short h) {
    union { uint32_t u; float f; } v; v.u = ((uint32_t)h) << 16;
    return v.f;
}
DEVFN float bfu_lo(uint32_t v) {
    union { uint32_t u; float f; } c; c.u = v << 16; return c.f;
}
DEVFN float bfu_hi(uint32_t v) {
    union { uint32_t u; float f; } c; c.u = v & 0xffff0000u; return c.f;
}
DEVFN uint32_t cvtpk(float lo, float hi) {
    uint32_t r;
    asm("v_cvt_pk_bf16_f32 %0, %1, %2" : "=v"(r) : "v"(lo), "v"(hi));
    return r;
}

DEVFN void gload16(const void* g, void* l) {
    __builtin_amdgcn_global_load_lds(
        (const __attribute__((address_space(1))) unsigned int*)(uintptr_t)g,
        (__attribute__((address_space(3))) unsigned int*)(uint32_t)(uintptr_t)l,
        16, 0, 0);
}

DEVFN f32x4 mfma16(s16x8 a, s16x8 b, f32x4 c) {
    return __builtin_amdgcn_mfma_f32_16x16x32_bf16(a, b, c, 0, 0, 0);
}

// swizzled fragment read: tile rows are 128 B; XOR row-bits into 16B-slot bits
DEVFN s16x8 ldfrag(const unsigned short* base, int row, int cb) {
    return *(const s16x8*)((const char*)base + row * 128 + (cb ^ ((row & 7) << 4)));
}

// ---------------------------------------------------------------- fused prep
// One launch, heterogeneous block ranges (all paths byte-identical logic to
// the previous standalone kernels):
//   [0,3072)    : Wqkv transpose-convert (fp32 [1024][3072] -> bf16 [3072][1024])
//   [3072,4096) : Wo transpose-convert   (fp32 [1024][1024] -> bf16 [1024][1024])
//   [4096,5120) : cat = [mems;w] fp32 -> bf16 (grid-stride)
//   [5120,5632) : r_emb remap -> rb [n][jj][d] bf16 ; r_bias -> rbt [n][jj] f32
__global__ __launch_bounds__(256) void k_prep_all(const float* __restrict__ mems,
                                                  const float* __restrict__ w,
                                                  const float* __restrict__ r_emb,
                                                  const float* __restrict__ r_bias,
                                                  const float* __restrict__ Wqkv,
                                                  const float* __restrict__ Wo,
                                                  unsigned short* __restrict__ catb,
                                                  unsigned short* __restrict__ wqkvT,
                                                  unsigned short* __restrict__ woT,
                                                  unsigned short* __restrict__ rb,
                                                  float* __restrict__ rbt) {
    __shared__ float T[32][33];
    int bid = blockIdx.x, tid = threadIdx.x;
    if (bid < 4096) {
        // transpose-convert path
        const float* in;
        unsigned short* out;
        int R = 1024, C;
        int c0, r0;
        if (bid < 3072) {
            in = Wqkv; out = wqkvT; C = 3072;
            c0 = (bid % 96) * 32; r0 = (bid / 96) * 32;
        } else {
            int b2 = bid - 3072;
            in = Wo; out = woT; C = 1024;
            c0 = (b2 & 31) * 32; r0 = (b2 >> 5) * 32;
        }
        int tx = tid & 31, ty = tid >> 5;  // (32,8)
#pragma unroll
        for (int i = 0; i < 4; ++i) {
            int r = ty * 4 + i;
            T[r][tx] = in[(size_t)(r0 + r) * C + c0 + tx];
        }
        __syncthreads();
#pragma unroll
        for (int i = 0; i < 4; ++i) {
            int r = ty * 4 + i;
            out[(size_t)(c0 + r) * R + r0 + tx] = f2bf(T[tx][r]);
        }
    } else if (bid < 5120) {
        // cat convert: 1024 blocks, grid-stride over 2097152 float4s
        long long i0 = (long long)(bid - 4096) * 256 + tid;
        for (long long i = i0; i < 2097152; i += 262144) {
            float4 v = (i < 1048576) ? ((const float4*)mems)[i] : ((const float4*)w)[i - 1048576];
            ushort4 o = make_ushort4(f2bf(v.x), f2bf(v.y), f2bf(v.z), f2bf(v.w));
            ((ushort4*)catb)[i] = o;
        }
    } else {
        // remap: 512 blocks
        long long o0 = (long long)(bid - 5120) * 256 + tid;
        for (long long o = o0; o < 2097152; o += 131072) {
            int n = (int)(o >> 17);
            int jj = (int)((o >> 6) & 2047);
            int d = (int)(o & 63);
            rb[o] = f2bf(r_emb[((size_t)jj * 16 + n) * 64 + d]);
        }
        for (long long o = o0; o < 32768; o += 131072)
            rbt[o] = r_bias[(size_t)(o & 2047) * 16 + (o >> 11)];
    }
}

// vb [bn][j][d] -> vt [bn][d][j]  (bf16, 64x64 tiles)
__global__ __launch_bounds__(256) void k_vtrans(const unsigned short* __restrict__ vb,
                                                unsigned short* __restrict__ vt) {
    __shared__ unsigned short T[64][72];
    int bn = blockIdx.y;
    int j0 = blockIdx.x * 64;
    int tid = threadIdx.x;
    int r = tid >> 2, cq = (tid & 3) * 16;
    size_t base = (size_t)bn * 131072;
    const unsigned short* src = vb + base + (size_t)(j0 + r) * 64 + cq;
    *(s16x8*)&T[r][cq] = *(const s16x8*)src;
    *(s16x8*)&T[r][cq + 8] = *(const s16x8*)(src + 8);
    __syncthreads();
    int d = r, jq = cq;
    s16x8 o0, o1;
#pragma unroll
    for (int t = 0; t < 8; ++t) { o0[t] = (short)T[jq + t][d]; o1[t] = (short)T[jq + 8 + t][d]; }
    unsigned short* dst = vt + base + (size_t)d * 2048 + j0 + jq;
    *(s16x8*)dst = o0;
    *(s16x8*)(dst + 8) = o1;
}

// ---------------------------------------------------------------- GEMM
// C = A(M x K, bf16 row-major) * B^T, B given transposed [N][K] bf16.
// 128x128 tile, BK=64, 4 waves (2x2), swizzled LDS.
// MODE 0 (QKV): 1D grid of 1280 blocks with dead-tile remap.
// MODE 1 (out proj): 2D grid, epilogue adds residual.
template <int MODE>
__global__ __launch_bounds__(256) void k_gemm(const unsigned short* __restrict__ A,
                                              const unsigned short* __restrict__ B,
                                              int K, int N,
                                              const float* __restrict__ wres,
                                              float* __restrict__ outf,
                                              unsigned short* __restrict__ qb,
                                              unsigned short* __restrict__ kb,
                                              unsigned short* __restrict__ vb) {
    __shared__ unsigned short As[128 * 64];
    __shared__ unsigned short Bs[128 * 64];
    int tid = threadIdx.x, lane = tid & 63, wid = tid >> 6;
    int l15 = lane & 15, l16 = lane >> 4;
    int m0, n0;
    if (MODE == 0) {
        int bid = blockIdx.x;
        if (bid < 1024) {
            m0 = (bid >> 4) * 128;
            n0 = (8 + (bid & 15)) * 128;
        } else {
            int q = bid - 1024;
            m0 = (32 + (q >> 3)) * 128;
            n0 = (q & 7) * 128;
        }
    } else {
        m0 = blockIdx.y * 128;
        n0 = blockIdx.x * 128;
    }
    int wr = wid >> 1, wc = wid & 1;
    f32x4 acc[4][4];
#pragma unroll
    for (int a = 0; a < 4; ++a)
#pragma unroll
        for (int b = 0; b < 4; ++b) acc[a][b] = f32x4{0.f, 0.f, 0.f, 0.f};

    for (int k0 = 0; k0 < K; k0 += 64) {
        __syncthreads();
#pragma unroll
        for (int it = 0; it < 4; ++it) {
            int slot = it * 4 + wid;
            int elem = slot * 512 + lane * 8;
            int row = elem >> 6;
            int colb = (lane & 7) * 16;
            int scol = (colb ^ ((row & 7) << 4)) >> 1;
            gload16(A + (size_t)(m0 + row) * K + k0 + scol, (char*)As + (size_t)slot * 1024);
            gload16(B + (size_t)(n0 + row) * K + k0 + scol, (char*)Bs + (size_t)slot * 1024);
        }
        asm volatile("s_waitcnt vmcnt(0)" ::: "memory");
        __syncthreads();
#pragma unroll
        for (int kc = 0; kc < 2; ++kc) {
            s16x8 af[4], bfr[4];
#pragma unroll
            for (int f = 0; f < 4; ++f)
                af[f] = ldfrag(As, wr * 64 + f * 16 + l15, kc * 64 + l16 * 16);
#pragma unroll
            for (int f = 0; f < 4; ++f)
                bfr[f] = ldfrag(Bs, wc * 64 + f * 16 + l15, kc * 64 + l16 * 16);
#pragma unroll
            for (int fm = 0; fm < 4; ++fm)
#pragma unroll
                for (int fn = 0; fn < 4; ++fn)
                    acc[fm][fn] = mfma16(af[fm], bfr[fn], acc[fm][fn]);
        }
    }
#pragma unroll
    for (int fm = 0; fm < 4; ++fm)
#pragma unroll
        for (int fn = 0; fn < 4; ++fn)
#pragma unroll
            for (int r = 0; r < 4; ++r) {
                int row = m0 + wr * 64 + fm * 16 + l16 * 4 + r;
                int col = n0 + wc * 64 + fn * 16 + l15;
                float v = acc[fm][fn][r];
                if (MODE == 0) {
                    int t = row >> 2, bb = row & 3;
                    if (col < 1024) {
                        if (t >= 1024) {
                            int nn = col >> 6, d = col & 63;
                            qb[((size_t)(bb * 16 + nn) * 1024 + (t - 1024)) * 64 + d] = f2bf(v);
                        }
                    } else if (col < 2048) {
                        int c2 = col - 1024, nn = c2 >> 6, d = c2 & 63;
                        kb[((size_t)(bb * 16 + nn) * 2048 + t) * 64 + d] = f2bf(v);
                    } else {
                        int c2 = col - 2048, nn = c2 >> 6, d = c2 & 63;
                        vb[((size_t)(bb * 16 + nn) * 2048 + t) * 64 + d] = f2bf(v);
                    }
                } else {
                    size_t o = (size_t)row * N + col;
                    outf[o] = v + wres[o];
                }
            }
}

// ---------------------------------------------------------------- attention
// r12 structure (best measured: 132 us): paired i-tiles, tri-buffer Rs,
// single barrier, skewed El (stride 20), Ps aliased (stride 68), ls via
// ones-MFMA, T13 defer-max THR=8, prefetch AFTER AC (loop-top issue
// regressed in r14: compiler vmcnt-orders prefetch LDS-writes vs E ds_reads).
__global__ __launch_bounds__(256) void k_attn(const unsigned short* __restrict__ qb,
                                              const unsigned short* __restrict__ kb,
                                              const unsigned short* __restrict__ vt,
                                              const unsigned short* __restrict__ rb,
                                              const float* __restrict__ rbt,
                                              const float* __restrict__ r_w_bias,
                                              unsigned short* __restrict__ av) {
    __shared__ unsigned short Ks[2][4096];   // [buf][jf][d] swizzled   16 KB
    __shared__ unsigned short Vs[2][4096];   // [buf][d][jf] swizzled   16 KB
    __shared__ unsigned short Rs[192 * 64];  // tri-buffer, swizzled    24 KB
    __shared__ unsigned short Elp[4][1920];  // El pool (Ps aliased)    15 KB
    __shared__ float rbs[192];               // tri-buffer band bias   .75 KB

    const float SC = 0.18033688f;  // 0.125 * log2(e)
    int tid = threadIdx.x, lane = tid & 63, wid = tid >> 6;
    int l15 = lane & 15, l16 = lane >> 4;
    int qr0 = l16 * 4;
    int bn = blockIdx.y, b = bn >> 4, n = bn & 15;
    size_t bq = (size_t)bn * 65536;
    size_t bk = (size_t)bn * 131072;
    int rbase = 48 - wid * 16;              // wave band-window start offset
    int lrow = lane >> 3;                   // dest row within an 8-row group
    int colb = (lane & 7) * 16;             // dest byte col
    int scolE = (colb ^ (lrow << 4)) >> 1;  // swizzled source col (elements)

    // loop-invariant LDS addresses (all further offsets are immediates)
    unsigned short* ElW = &Elp[wid][20 * l15 + 21 * qr0];          // + fe*320 + r*21
    const unsigned short* ElR = &Elp[wid][20 * (l15 + 15) + qr0];  // + fn*320, b64
    unsigned short* PsW = &Elp[wid][qr0 * 68 + l15];               // + fn*16 + r*68
    const unsigned short* PsR = &Elp[wid][l15 * 68];               // + kc*32 + l16*8

    s16x8 ones;
#pragma unroll
    for (int t = 0; t < 8; ++t) ones[t] = (short)0x3F80;  // bf16 1.0

    for (int h = 0; h < 2; ++h) {
        int it8 = h ? 15 - (int)blockIdx.x : (int)blockIdx.x;
        int i0 = it8 * 64;
        int njt = it8 + 17;
        int jjb = 960 - i0;  // band base: jj = jjb + j0 + rbase + bcol

        // Q fragments (pre-scaled by SC)
        s16x8 aq[2], aqr[2];
        {
            int qrow = i0 + wid * 16 + l15;
#pragma unroll
            for (int kc = 0; kc < 2; ++kc) {
                s16x8 qv = *(const s16x8*)(qb + bq + (size_t)qrow * 64 + kc * 32 + l16 * 8);
                s16x8 q1, q2;
#pragma unroll
                for (int t = 0; t < 8; ++t) {
                    float f = bf2f((unsigned short)qv[t]);
                    float rw = r_w_bias[n * 64 + kc * 32 + l16 * 8 + t];
                    q1[t] = (short)f2bf(f * SC);
                    q2[t] = (short)f2bf((f + rw) * SC);
                }
                aq[kc] = q1;
                aqr[kc] = q2;
            }
        }

        float m_[4];
        f32x4 accO[4], accL;
#pragma unroll
        for (int r = 0; r < 4; ++r) m_[r] = -3.0e38f;
#pragma unroll
        for (int f = 0; f < 4; ++f) accO[f] = f32x4{0.f, 0.f, 0.f, 0.f};
        accL = f32x4{0.f, 0.f, 0.f, 0.f};

        // ---- prologue: K/V tile 0, R band rows [0,128), rbs ----
#pragma unroll
        for (int q = 0; q < 2; ++q) {
            int s = wid * 2 + q;
            int row = s * 8 + lrow;
            gload16(kb + bk + (size_t)row * 64 + scolE, (char*)Ks[0] + s * 1024);
            gload16(vt + bk + (size_t)row * 2048 + scolE, (char*)Vs[0] + s * 1024);
        }
#pragma unroll
        for (int q = 0; q < 4; ++q) {
            int s = wid * 4 + q;
            int jju = jjb + s * 8 + lrow;  // <= 1087, no clamp needed
            gload16(rb + (size_t)n * 131072 + (size_t)jju * 64 + scolE,
                    (char*)Rs + (s * 8) * 128);
        }
        if (tid < 128) {
            int jju = jjb + tid;
            rbs[tid] = SC * rbt[(size_t)n * 2048 + jju];
        }
        __syncthreads();

        int cur = 0, rsb = 0;
        for (int jt = 0; jt < njt; ++jt) {
            int j0 = jt * 64;
            int jjc = jjb + j0;
            bool pf = (jt + 1 < njt);

            // E = q . R_window^T (16x80/wave) -> skewed El, rbias+mask folded
            __builtin_amdgcn_s_setprio(1);
#pragma unroll
            for (int fe = 0; fe < 5; ++fe) {
                int row = rsb + rbase + fe * 16 + l15;
                if (row >= 192) row -= 192;
                f32x4 e = f32x4{0.f, 0.f, 0.f, 0.f};
                e = mfma16(aq[0], ldfrag(Rs, row, l16 * 16), e);
                e = mfma16(aq[1], ldfrag(Rs, row, 64 + l16 * 16), e);
                float rbv = rbs[row];
                uint32_t p01 = cvtpk(e[0] + rbv, e[1] + rbv);
                uint32_t p23 = cvtpk(e[2] + rbv, e[3] + rbv);
                ElW[fe * 320] = (unsigned short)p01;
                ElW[fe * 320 + 21] = (unsigned short)(p01 >> 16);
                ElW[fe * 320 + 42] = (unsigned short)p23;
                ElW[fe * 320 + 63] = (unsigned short)(p23 >> 16);
            }
            // AC = (q + r_w_bias) . K^T
            f32x4 sAC[4];
#pragma unroll
            for (int fn = 0; fn < 4; ++fn) {
                f32x4 a = f32x4{0.f, 0.f, 0.f, 0.f};
#pragma unroll
                for (int kc = 0; kc < 2; ++kc)
                    a = mfma16(aqr[kc], ldfrag(Ks[cur], fn * 16 + l15, kc * 64 + l16 * 16), a);
                sAC[fn] = a;
            }
            __builtin_amdgcn_s_setprio(0);

            // prefetch issue (flies under softmax + PV + barrier)
            if (pf) {
                int j0n = j0 + 64;
#pragma unroll
                for (int q = 0; q < 2; ++q) {
                    int s = wid * 2 + q;
                    int row = s * 8 + lrow;
                    gload16(kb + bk + (size_t)(j0n + row) * 64 + scolE,
                            (char*)Ks[cur ^ 1] + s * 1024);
                    gload16(vt + bk + (size_t)row * 2048 + j0n + scolE,
                            (char*)Vs[cur ^ 1] + s * 1024);
                }
#pragma unroll
                for (int q = 0; q < 2; ++q) {
                    int s = wid * 2 + q;
                    int w = rsb + 128 + s * 8;
                    if (w >= 192) w -= 192;
                    int jju = jjc + 128 + s * 8 + lrow;
                    int jja = jju > 2047 ? 2047 : jju;  // clamp source only
                    gload16(rb + (size_t)n * 131072 + (size_t)jja * 64 + scolE,
                            (char*)Rs + w * 128);
                }
                if (tid < 64) {
                    int w = rsb + 128 + tid;
                    if (w >= 192) w -= 192;
                    int jju = jjc + 128 + tid;
                    rbs[w] = (jju <= 2047) ? SC * rbt[(size_t)n * 2048 + jju] : -1.0e30f;
                }
            }

            // softmax: scores via 4x b64 diagonal reads; defer-max THR=8
            float pe[4][4];
            float lmax[4] = {-3.0e38f, -3.0e38f, -3.0e38f, -3.0e38f};
#pragma unroll
            for (int fn = 0; fn < 4; ++fn) {
                uint2 ev = *(const uint2*)(ElR + fn * 320);
                pe[fn][0] = sAC[fn][0] + bfu_lo(ev.x);
                pe[fn][1] = sAC[fn][1] + bfu_hi(ev.x);
                pe[fn][2] = sAC[fn][2] + bfu_lo(ev.y);
                pe[fn][3] = sAC[fn][3] + bfu_hi(ev.y);
#pragma unroll
                for (int r = 0; r < 4; ++r) lmax[r] = fmaxf(lmax[r], pe[fn][r]);
            }
            bool need = (lmax[0] > m_[0] + 8.f) | (lmax[1] > m_[1] + 8.f) |
                        (lmax[2] > m_[2] + 8.f) | (lmax[3] > m_[3] + 8.f);
            if (__any(need)) {
#pragma unroll
                for (int msk = 1; msk <= 8; msk <<= 1)
#pragma unroll
                    for (int r = 0; r < 4; ++r)
                        lmax[r] = fmaxf(lmax[r], __shfl_xor(lmax[r], msk, 64));
#pragma unroll
                for (int r = 0; r < 4; ++r) {
                    float mn = fmaxf(m_[r], lmax[r]);
                    float alpha = __builtin_exp2f(m_[r] - mn);
                    m_[r] = mn;
                    accL[r] *= alpha;
#pragma unroll
                    for (int f = 0; f < 4; ++f) accO[f][r] *= alpha;
                }
            }
            // all El reads above complete before these aliased Ps writes
#pragma unroll
            for (int fn = 0; fn < 4; ++fn) {
                float e0 = __builtin_exp2f(pe[fn][0] - m_[0]);
                float e1 = __builtin_exp2f(pe[fn][1] - m_[1]);
                float e2 = __builtin_exp2f(pe[fn][2] - m_[2]);
                float e3 = __builtin_exp2f(pe[fn][3] - m_[3]);
                uint32_t a = cvtpk(e0, e1);
                uint32_t c = cvtpk(e2, e3);
                PsW[fn * 16] = (unsigned short)a;
                PsW[fn * 16 + 68] = (unsigned short)(a >> 16);
                PsW[fn * 16 + 136] = (unsigned short)c;
                PsW[fn * 16 + 204] = (unsigned short)(c >> 16);
            }

            // PV (+ row-sum via ones-MFMA); Ps rows 8B-aligned -> 2x b64
            __builtin_amdgcn_s_setprio(1);
#pragma unroll
            for (int kc = 0; kc < 2; ++kc) {
                const uint2* pp = (const uint2*)(PsR + kc * 32 + l16 * 8);
                union { uint2 u2[2]; s16x8 v; } uu;
                uu.u2[0] = pp[0];
                uu.u2[1] = pp[1];
                s16x8 pa = uu.v;
                accL = mfma16(pa, ones, accL);
#pragma unroll
                for (int fd = 0; fd < 4; ++fd)
                    accO[fd] = mfma16(pa, ldfrag(Vs[cur], fd * 16 + l15, kc * 64 + l16 * 16),
                                      accO[fd]);
            }
            __builtin_amdgcn_s_setprio(0);

            __syncthreads();  // single barrier: drains prefetch, publishes all buffers
            cur ^= 1;
            rsb += 64;
            if (rsb == 192) rsb = 0;
        }

        // write attn_vec row-normalized, bf16, layout [i*4+b][n*64+d]
#pragma unroll
        for (int r = 0; r < 4; ++r) {
            float inv = 1.f / accL[r];
            int ig = i0 + wid * 16 + qr0 + r;
#pragma unroll
            for (int fd = 0; fd < 4; ++fd)
                av[((size_t)ig * 4 + b) * 1024 + n * 64 + fd * 16 + l15] = f2bf(accO[fd][r] * inv);
        }
    }
}

// ---------------------------------------------------------------- layernorm (in-place on d_out)
__global__ __launch_bounds__(256) void k_ln(float* __restrict__ y, const float* __restrict__ g,
                                            const float* __restrict__ bta) {
    int row = blockIdx.x, tid = threadIdx.x;
    int lane = tid & 63, wid = tid >> 6;
    float4 v = ((const float4*)(y + (size_t)row * 1024))[tid];
    float s = v.x + v.y + v.z + v.w;
    float sq = v.x * v.x + v.y * v.y + v.z * v.z + v.w * v.w;
#pragma unroll
    for (int msk = 1; msk <= 32; msk <<= 1) {
        s += __shfl_xor(s, msk, 64);
        sq += __shfl_xor(sq, msk, 64);
    }
    __shared__ float red[2][4];
    if (lane == 0) { red[0][wid] = s; red[1][wid] = sq; }
    __syncthreads();
    s = red[0][0] + red[0][1] + red[0][2] + red[0][3];
    sq = red[1][0] + red[1][1] + red[1][2] + red[1][3];
    float mu = s * (1.f / 1024.f);
    float var = sq * (1.f / 1024.f) - mu * mu;
    float rs = rsqrtf(var + 1e-5f);
    float4 gv = ((const float4*)g)[tid];
    float4 bv = ((const float4*)bta)[tid];
    float4 o;
    o.x = (v.x - mu) * rs * gv.x + bv.x;
    o.y = (v.y - mu) * rs * gv.y + bv.y;
    o.z = (v.z - mu) * rs * gv.z + bv.z;
    o.w = (v.w - mu) * rs * gv.w + bv.w;
    ((float4*)(y + (size_t)row * 1024))[tid] = o;
}

// ---------------------------------------------------------------- launch
extern "C" void kernel_launch(void* const* d_in, const int* in_sizes, int n_in,
                              void* d_out, int out_size, void* d_ws, size_t ws_size,
                              hipStream_t stream) {
    const float* w      = (const float*)d_in[0];
    const float* mems   = (const float*)d_in[1];
    const float* r_emb  = (const float*)d_in[2];
    const float* r_wb   = (const float*)d_in[3];
    const float* r_bias = (const float*)d_in[4];
    const float* Wqkv   = (const float*)d_in[5];
    const float* Wo     = (const float*)d_in[6];
    const float* ln_g   = (const float*)d_in[7];
    const float* ln_b   = (const float*)d_in[8];
    float* out = (float*)d_out;

    char* p = (char*)d_ws;
    auto alloc = [&](size_t bytes) {
        char* q = p;
        p += (bytes + 255) & ~(size_t)255;
        return q;
    };
    unsigned short* catb  = (unsigned short*)alloc(8192ull * 1024 * 2);      // 16 MB
    unsigned short* wqkvT = (unsigned short*)alloc(3072ull * 1024 * 2);      // 6 MB
    unsigned short* woT   = (unsigned short*)alloc(1024ull * 1024 * 2);      // 2 MB
    unsigned short* rb    = (unsigned short*)alloc(16ull * 2048 * 64 * 2);   // 4 MB
    float*          rbt   = (float*)alloc(16ull * 2048 * 4);                 // 128 KB
    unsigned short* qbuf  = (unsigned short*)alloc(64ull * 1024 * 64 * 2);   // 8 MB
    unsigned short* kbuf  = (unsigned short*)alloc(64ull * 2048 * 64 * 2);   // 16 MB
    unsigned short* vbuf  = (unsigned short*)alloc(64ull * 2048 * 64 * 2);   // 16 MB
    unsigned short* av    = (unsigned short*)alloc(4096ull * 1024 * 2);      // 8 MB
    unsigned short* vtb = catb;  // catb dead after GEMM1

    k_prep_all<<<5632, 256, 0, stream>>>(mems, w, r_emb, r_bias, Wqkv, Wo,
                                         catb, wqkvT, woT, rb, rbt);

    // GEMM1: 1280 blocks, dead-tile-skipping remap (mem-row Q tiles skipped)
    k_gemm<0><<<1280, 256, 0, stream>>>(catb, wqkvT, 1024, 3072,
                                        nullptr, nullptr, qbuf, kbuf, vbuf);
    k_vtrans<<<dim3(32, 64), 256, 0, stream>>>(vbuf, vtb);
    k_attn<<<dim3(8, 64), 256, 0, stream>>>(qbuf, kbuf, vtb, rb, rbt, r_wb, av);
    k_gemm<1><<<dim3(8, 32), 256, 0, stream>>>(av, woT, 1024, 1024,
                                               w, out, nullptr, nullptr, nullptr);
    k_ln<<<4096, 256, 0, stream>>>(out, ln_g, ln_b);
}

// Round 16
// 238.692 us; speedup vs baseline: 1.0751x; 1.0050x over previous
//
#include <hip/hip_runtime.h>
#include <hip/hip_bf16.h>
#include <stdint.h>

typedef __attribute__((ext_vector_type(8))) short s16x8;
typedef __attribute__((ext_vector_type(4))) float f32x4;

#define DEVFN static __device__ __forceinline__

DEVFN unsigned short f2bf(float f) {
    union { float f; uint32_t u; } v; v.f = f;
    uint32_t u = v.u;
    uint32_t r = (u + 0x7fffu + ((u >> 16) & 1u)) >> 16;
    return (unsigned short)r;
}
DEVFN float bf2f(unsigned short h) {
    union { uint32_t u; float f; } v; v.u = ((uint32_t)h) << 16;
    return v.f;
}
DEVFN float bfu_lo(uint32_t v) {
    union { uint32_t u; float f; } c; c.u = v << 16; return c.f;
}
DEVFN float bfu_hi(uint32_t v) {
    union { uint32_t u; float f; } c; c.u = v & 0xffff0000u; return c.f;
}
DEVFN uint32_t cvtpk(float lo, float hi) {
    uint32_t r;
    asm("v_cvt_pk_bf16_f32 %0, %1, %2" : "=v"(r) : "v"(lo), "v"(hi));
    return r;
}

DEVFN void gload16(const void* g, void* l) {
    __builtin_amdgcn_global_load_lds(
        (const __attribute__((address_space(1))) unsigned int*)(uintptr_t)g,
        (__attribute__((address_space(3))) unsigned int*)(uint32_t)(uintptr_t)l,
        16, 0, 0);
}

DEVFN f32x4 mfma16(s16x8 a, s16x8 b, f32x4 c) {
    return __builtin_amdgcn_mfma_f32_16x16x32_bf16(a, b, c, 0, 0, 0);
}

// swizzled fragment read: tile rows are 128 B; XOR row-bits into 16B-slot bits
DEVFN s16x8 ldfrag(const unsigned short* base, int row, int cb) {
    return *(const s16x8*)((const char*)base + row * 128 + (cb ^ ((row & 7) << 4)));
}

// ---------------------------------------------------------------- fused prep
//   [0,3072)    : Wqkv transpose-convert (fp32 [1024][3072] -> bf16 [3072][1024])
//   [3072,4096) : Wo transpose-convert   (fp32 [1024][1024] -> bf16 [1024][1024])
//   [4096,5120) : cat = [mems;w] fp32 -> bf16 (grid-stride)
//   [5120,5632) : r_emb remap -> rb [n][jj][d] bf16 ; r_bias -> rbt [n][jj] f32
__global__ __launch_bounds__(256) void k_prep_all(const float* __restrict__ mems,
                                                  const float* __restrict__ w,
                                                  const float* __restrict__ r_emb,
                                                  const float* __restrict__ r_bias,
                                                  const float* __restrict__ Wqkv,
                                                  const float* __restrict__ Wo,
                                                  unsigned short* __restrict__ catb,
                                                  unsigned short* __restrict__ wqkvT,
                                                  unsigned short* __restrict__ woT,
                                                  unsigned short* __restrict__ rb,
                                                  float* __restrict__ rbt) {
    __shared__ float T[32][33];
    int bid = blockIdx.x, tid = threadIdx.x;
    if (bid < 4096) {
        const float* in;
        unsigned short* out;
        int R = 1024, C;
        int c0, r0;
        if (bid < 3072) {
            in = Wqkv; out = wqkvT; C = 3072;
            c0 = (bid % 96) * 32; r0 = (bid / 96) * 32;
        } else {
            int b2 = bid - 3072;
            in = Wo; out = woT; C = 1024;
            c0 = (b2 & 31) * 32; r0 = (b2 >> 5) * 32;
        }
        int tx = tid & 31, ty = tid >> 5;
#pragma unroll
        for (int i = 0; i < 4; ++i) {
            int r = ty * 4 + i;
            T[r][tx] = in[(size_t)(r0 + r) * C + c0 + tx];
        }
        __syncthreads();
#pragma unroll
        for (int i = 0; i < 4; ++i) {
            int r = ty * 4 + i;
            out[(size_t)(c0 + r) * R + r0 + tx] = f2bf(T[tx][r]);
        }
    } else if (bid < 5120) {
        long long i0 = (long long)(bid - 4096) * 256 + tid;
        for (long long i = i0; i < 2097152; i += 262144) {
            float4 v = (i < 1048576) ? ((const float4*)mems)[i] : ((const float4*)w)[i - 1048576];
            ushort4 o = make_ushort4(f2bf(v.x), f2bf(v.y), f2bf(v.z), f2bf(v.w));
            ((ushort4*)catb)[i] = o;
        }
    } else {
        long long o0 = (long long)(bid - 5120) * 256 + tid;
        for (long long o = o0; o < 2097152; o += 131072) {
            int n = (int)(o >> 17);
            int jj = (int)((o >> 6) & 2047);
            int d = (int)(o & 63);
            rb[o] = f2bf(r_emb[((size_t)jj * 16 + n) * 64 + d]);
        }
        for (long long o = o0; o < 32768; o += 131072)
            rbt[o] = r_bias[(size_t)(o & 2047) * 16 + (o >> 11)];
    }
}

// ---------------------------------------------------------------- GEMM
// C = A(M x K, bf16 row-major) * B^T, B given transposed [N][K] bf16.
// 128x128 tile, BK=64, 4 waves (2x2), swizzled LDS.
// MODE 0 (QKV): 1D grid of 1280 blocks with dead-tile remap. V-tiles
//   (n0>=2048) transpose through the (dead) LDS in the epilogue and write
//   vt[bn][d][t] DIRECTLY (k_vtrans eliminated; vt must NOT alias catb).
// MODE 1 (out proj): 2D grid, epilogue adds residual.
template <int MODE>
__global__ __launch_bounds__(256) void k_gemm(const unsigned short* __restrict__ A,
                                              const unsigned short* __restrict__ B,
                                              int K, int N,
                                              const float* __restrict__ wres,
                                              float* __restrict__ outf,
                                              unsigned short* __restrict__ qb,
                                              unsigned short* __restrict__ kb,
                                              unsigned short* __restrict__ vtb) {
    __shared__ unsigned short smem[128 * 128];  // 32 KB: As | Bs ; reused by V-epilogue
    unsigned short* As = smem;
    unsigned short* Bs = smem + 8192;
    int tid = threadIdx.x, lane = tid & 63, wid = tid >> 6;
    int l15 = lane & 15, l16 = lane >> 4;
    int m0, n0;
    if (MODE == 0) {
        int bid = blockIdx.x;
        if (bid < 1024) {
            m0 = (bid >> 4) * 128;
            n0 = (8 + (bid & 15)) * 128;
        } else {
            int q = bid - 1024;
            m0 = (32 + (q >> 3)) * 128;
            n0 = (q & 7) * 128;
        }
    } else {
        m0 = blockIdx.y * 128;
        n0 = blockIdx.x * 128;
    }
    int wr = wid >> 1, wc = wid & 1;
    f32x4 acc[4][4];
#pragma unroll
    for (int a = 0; a < 4; ++a)
#pragma unroll
        for (int b = 0; b < 4; ++b) acc[a][b] = f32x4{0.f, 0.f, 0.f, 0.f};

    for (int k0 = 0; k0 < K; k0 += 64) {
        __syncthreads();
#pragma unroll
        for (int it = 0; it < 4; ++it) {
            int slot = it * 4 + wid;
            int elem = slot * 512 + lane * 8;
            int row = elem >> 6;
            int colb = (lane & 7) * 16;
            int scol = (colb ^ ((row & 7) << 4)) >> 1;
            gload16(A + (size_t)(m0 + row) * K + k0 + scol, (char*)As + (size_t)slot * 1024);
            gload16(B + (size_t)(n0 + row) * K + k0 + scol, (char*)Bs + (size_t)slot * 1024);
        }
        asm volatile("s_waitcnt vmcnt(0)" ::: "memory");
        __syncthreads();
#pragma unroll
        for (int kc = 0; kc < 2; ++kc) {
            s16x8 af[4], bfr[4];
#pragma unroll
            for (int f = 0; f < 4; ++f)
                af[f] = ldfrag(As, wr * 64 + f * 16 + l15, kc * 64 + l16 * 16);
#pragma unroll
            for (int f = 0; f < 4; ++f)
                bfr[f] = ldfrag(Bs, wc * 64 + f * 16 + l15, kc * 64 + l16 * 16);
#pragma unroll
            for (int fm = 0; fm < 4; ++fm)
#pragma unroll
                for (int fn = 0; fn < 4; ++fn)
                    acc[fm][fn] = mfma16(af[fm], bfr[fn], acc[fm][fn]);
        }
    }

    if (MODE == 0 && n0 >= 2048) {
        // ---- V-tile epilogue: LDS transpose -> vt[bn][d][t] direct ----
        // row = m0+wr*64+fm*16+l16*4+r : bb=row&3=r, t_local=wr*16+fm*4+l16
        // col = n0+wc*64+fn*16+l15     : d=col&63, nn=((n0-2048)>>6)+half
        int nnBase = (n0 - 2048) >> 6;
        int tB = m0 >> 2;
#pragma unroll
        for (int half = 0; half < 2; ++half) {
            __syncthreads();  // LDS (As/Bs or prior half) fully consumed
            if (wc == half) {
#pragma unroll
                for (int fn = 0; fn < 4; ++fn) {
                    int cl = fn * 16 + l15;  // 0..63
#pragma unroll
                    for (int fm = 0; fm < 4; ++fm) {
                        int tl = wr * 16 + fm * 4 + l16;  // 0..31
#pragma unroll
                        for (int r = 0; r < 4; ++r)
                            smem[cl * 136 + r * 32 + tl] = f2bf(acc[fm][fn][r]);
                    }
                }
            }
            __syncthreads();
            int cl = tid & 63, bb = tid >> 6;  // one (d, batch) task per thread
            const unsigned short* src = &smem[cl * 136 + bb * 32];
            s16x8 v0 = *(const s16x8*)src;
            s16x8 v1 = *(const s16x8*)(src + 8);
            s16x8 v2 = *(const s16x8*)(src + 16);
            s16x8 v3 = *(const s16x8*)(src + 24);
            unsigned short* dst = vtb + (size_t)(bb * 16 + nnBase + half) * 131072 +
                                  (size_t)cl * 2048 + tB;
            *(s16x8*)dst = v0;
            *(s16x8*)(dst + 8) = v1;
            *(s16x8*)(dst + 16) = v2;
            *(s16x8*)(dst + 24) = v3;
        }
        return;
    }

#pragma unroll
    for (int fm = 0; fm < 4; ++fm)
#pragma unroll
        for (int fn = 0; fn < 4; ++fn)
#pragma unroll
            for (int r = 0; r < 4; ++r) {
                int row = m0 + wr * 64 + fm * 16 + l16 * 4 + r;
                int col = n0 + wc * 64 + fn * 16 + l15;
                float v = acc[fm][fn][r];
                if (MODE == 0) {
                    int t = row >> 2, bb = row & 3;
                    if (col < 1024) {
                        if (t >= 1024) {
                            int nn = col >> 6, d = col & 63;
                            qb[((size_t)(bb * 16 + nn) * 1024 + (t - 1024)) * 64 + d] = f2bf(v);
                        }
                    } else {
                        int c2 = col - 1024, nn = c2 >> 6, d = c2 & 63;
                        kb[((size_t)(bb * 16 + nn) * 2048 + t) * 64 + d] = f2bf(v);
                    }
                } else {
                    size_t o = (size_t)row * N + col;
                    outf[o] = v + wres[o];
                }
            }
}

// ---------------------------------------------------------------- attention
// r12/r15 structure (best measured: 132 us): paired i-tiles, tri-buffer Rs,
// single barrier, skewed El (stride 20), Ps aliased (stride 68), ls via
// ones-MFMA, T13 defer-max THR=8, prefetch AFTER AC.
__global__ __launch_bounds__(256) void k_attn(const unsigned short* __restrict__ qb,
                                              const unsigned short* __restrict__ kb,
                                              const unsigned short* __restrict__ vt,
                                              const unsigned short* __restrict__ rb,
                                              const float* __restrict__ rbt,
                                              const float* __restrict__ r_w_bias,
                                              unsigned short* __restrict__ av) {
    __shared__ unsigned short Ks[2][4096];   // [buf][jf][d] swizzled   16 KB
    __shared__ unsigned short Vs[2][4096];   // [buf][d][jf] swizzled   16 KB
    __shared__ unsigned short Rs[192 * 64];  // tri-buffer, swizzled    24 KB
    __shared__ unsigned short Elp[4][1920];  // El pool (Ps aliased)    15 KB
    __shared__ float rbs[192];               // tri-buffer band bias   .75 KB

    const float SC = 0.18033688f;  // 0.125 * log2(e)
    int tid = threadIdx.x, lane = tid & 63, wid = tid >> 6;
    int l15 = lane & 15, l16 = lane >> 4;
    int qr0 = l16 * 4;
    int bn = blockIdx.y, b = bn >> 4, n = bn & 15;
    size_t bq = (size_t)bn * 65536;
    size_t bk = (size_t)bn * 131072;
    int rbase = 48 - wid * 16;              // wave band-window start offset
    int lrow = lane >> 3;                   // dest row within an 8-row group
    int colb = (lane & 7) * 16;             // dest byte col
    int scolE = (colb ^ (lrow << 4)) >> 1;  // swizzled source col (elements)

    // loop-invariant LDS addresses (all further offsets are immediates)
    unsigned short* ElW = &Elp[wid][20 * l15 + 21 * qr0];          // + fe*320 + r*21
    const unsigned short* ElR = &Elp[wid][20 * (l15 + 15) + qr0];  // + fn*320, b64
    unsigned short* PsW = &Elp[wid][qr0 * 68 + l15];               // + fn*16 + r*68
    const unsigned short* PsR = &Elp[wid][l15 * 68];               // + kc*32 + l16*8

    s16x8 ones;
#pragma unroll
    for (int t = 0; t < 8; ++t) ones[t] = (short)0x3F80;  // bf16 1.0

    for (int h = 0; h < 2; ++h) {
        int it8 = h ? 15 - (int)blockIdx.x : (int)blockIdx.x;
        int i0 = it8 * 64;
        int njt = it8 + 17;
        int jjb = 960 - i0;  // band base: jj = jjb + j0 + rbase + bcol

        // Q fragments (pre-scaled by SC)
        s16x8 aq[2], aqr[2];
        {
            int qrow = i0 + wid * 16 + l15;
#pragma unroll
            for (int kc = 0; kc < 2; ++kc) {
                s16x8 qv = *(const s16x8*)(qb + bq + (size_t)qrow * 64 + kc * 32 + l16 * 8);
                s16x8 q1, q2;
#pragma unroll
                for (int t = 0; t < 8; ++t) {
                    float f = bf2f((unsigned short)qv[t]);
                    float rw = r_w_bias[n * 64 + kc * 32 + l16 * 8 + t];
                    q1[t] = (short)f2bf(f * SC);
                    q2[t] = (short)f2bf((f + rw) * SC);
                }
                aq[kc] = q1;
                aqr[kc] = q2;
            }
        }

        float m_[4];
        f32x4 accO[4], accL;
#pragma unroll
        for (int r = 0; r < 4; ++r) m_[r] = -3.0e38f;
#pragma unroll
        for (int f = 0; f < 4; ++f) accO[f] = f32x4{0.f, 0.f, 0.f, 0.f};
        accL = f32x4{0.f, 0.f, 0.f, 0.f};

        // ---- prologue: K/V tile 0, R band rows [0,128), rbs ----
#pragma unroll
        for (int q = 0; q < 2; ++q) {
            int s = wid * 2 + q;
            int row = s * 8 + lrow;
            gload16(kb + bk + (size_t)row * 64 + scolE, (char*)Ks[0] + s * 1024);
            gload16(vt + bk + (size_t)row * 2048 + scolE, (char*)Vs[0] + s * 1024);
        }
#pragma unroll
        for (int q = 0; q < 4; ++q) {
            int s = wid * 4 + q;
            int jju = jjb + s * 8 + lrow;  // <= 1087, no clamp needed
            gload16(rb + (size_t)n * 131072 + (size_t)jju * 64 + scolE,
                    (char*)Rs + (s * 8) * 128);
        }
        if (tid < 128) {
            int jju = jjb + tid;
            rbs[tid] = SC * rbt[(size_t)n * 2048 + jju];
        }
        __syncthreads();

        int cur = 0, rsb = 0;
        for (int jt = 0; jt < njt; ++jt) {
            int j0 = jt * 64;
            int jjc = jjb + j0;
            bool pf = (jt + 1 < njt);

            // E = q . R_window^T (16x80/wave) -> skewed El, rbias+mask folded
            __builtin_amdgcn_s_setprio(1);
#pragma unroll
            for (int fe = 0; fe < 5; ++fe) {
                int row = rsb + rbase + fe * 16 + l15;
                if (row >= 192) row -= 192;
                f32x4 e = f32x4{0.f, 0.f, 0.f, 0.f};
                e = mfma16(aq[0], ldfrag(Rs, row, l16 * 16), e);
                e = mfma16(aq[1], ldfrag(Rs, row, 64 + l16 * 16), e);
                float rbv = rbs[row];
                uint32_t p01 = cvtpk(e[0] + rbv, e[1] + rbv);
                uint32_t p23 = cvtpk(e[2] + rbv, e[3] + rbv);
                ElW[fe * 320] = (unsigned short)p01;
                ElW[fe * 320 + 21] = (unsigned short)(p01 >> 16);
                ElW[fe * 320 + 42] = (unsigned short)p23;
                ElW[fe * 320 + 63] = (unsigned short)(p23 >> 16);
            }
            // AC = (q + r_w_bias) . K^T
            f32x4 sAC[4];
#pragma unroll
            for (int fn = 0; fn < 4; ++fn) {
                f32x4 a = f32x4{0.f, 0.f, 0.f, 0.f};
#pragma unroll
                for (int kc = 0; kc < 2; ++kc)
                    a = mfma16(aqr[kc], ldfrag(Ks[cur], fn * 16 + l15, kc * 64 + l16 * 16), a);
                sAC[fn] = a;
            }
            __builtin_amdgcn_s_setprio(0);

            // prefetch issue (flies under softmax + PV + barrier)
            if (pf) {
                int j0n = j0 + 64;
#pragma unroll
                for (int q = 0; q < 2; ++q) {
                    int s = wid * 2 + q;
                    int row = s * 8 + lrow;
                    gload16(kb + bk + (size_t)(j0n + row) * 64 + scolE,
                            (char*)Ks[cur ^ 1] + s * 1024);
                    gload16(vt + bk + (size_t)row * 2048 + j0n + scolE,
                            (char*)Vs[cur ^ 1] + s * 1024);
                }
#pragma unroll
                for (int q = 0; q < 2; ++q) {
                    int s = wid * 2 + q;
                    int w = rsb + 128 + s * 8;
                    if (w >= 192) w -= 192;
                    int jju = jjc + 128 + s * 8 + lrow;
                    int jja = jju > 2047 ? 2047 : jju;  // clamp source only
                    gload16(rb + (size_t)n * 131072 + (size_t)jja * 64 + scolE,
                            (char*)Rs + w * 128);
                }
                if (tid < 64) {
                    int w = rsb + 128 + tid;
                    if (w >= 192) w -= 192;
                    int jju = jjc + 128 + tid;
                    rbs[w] = (jju <= 2047) ? SC * rbt[(size_t)n * 2048 + jju] : -1.0e30f;
                }
            }

            // softmax: scores via 4x b64 diagonal reads; defer-max THR=8
            float pe[4][4];
            float lmax[4] = {-3.0e38f, -3.0e38f, -3.0e38f, -3.0e38f};
#pragma unroll
            for (int fn = 0; fn < 4; ++fn) {
                uint2 ev = *(const uint2*)(ElR + fn * 320);
                pe[fn][0] = sAC[fn][0] + bfu_lo(ev.x);
                pe[fn][1] = sAC[fn][1] + bfu_hi(ev.x);
                pe[fn][2] = sAC[fn][2] + bfu_lo(ev.y);
                pe[fn][3] = sAC[fn][3] + bfu_hi(ev.y);
#pragma unroll
                for (int r = 0; r < 4; ++r) lmax[r] = fmaxf(lmax[r], pe[fn][r]);
            }
            bool need = (lmax[0] > m_[0] + 8.f) | (lmax[1] > m_[1] + 8.f) |
                        (lmax[2] > m_[2] + 8.f) | (lmax[3] > m_[3] + 8.f);
            if (__any(need)) {
#pragma unroll
                for (int msk = 1; msk <= 8; msk <<= 1)
#pragma unroll
                    for (int r = 0; r < 4; ++r)
                        lmax[r] = fmaxf(lmax[r], __shfl_xor(lmax[r], msk, 64));
#pragma unroll
                for (int r = 0; r < 4; ++r) {
                    float mn = fmaxf(m_[r], lmax[r]);
                    float alpha = __builtin_exp2f(m_[r] - mn);
                    m_[r] = mn;
                    accL[r] *= alpha;
#pragma unroll
                    for (int f = 0; f < 4; ++f) accO[f][r] *= alpha;
                }
            }
            // all El reads above complete before these aliased Ps writes
#pragma unroll
            for (int fn = 0; fn < 4; ++fn) {
                float e0 = __builtin_exp2f(pe[fn][0] - m_[0]);
                float e1 = __builtin_exp2f(pe[fn][1] - m_[1]);
                float e2 = __builtin_exp2f(pe[fn][2] - m_[2]);
                float e3 = __builtin_exp2f(pe[fn][3] - m_[3]);
                uint32_t a = cvtpk(e0, e1);
                uint32_t c = cvtpk(e2, e3);
                PsW[fn * 16] = (unsigned short)a;
                PsW[fn * 16 + 68] = (unsigned short)(a >> 16);
                PsW[fn * 16 + 136] = (unsigned short)c;
                PsW[fn * 16 + 204] = (unsigned short)(c >> 16);
            }

            // PV (+ row-sum via ones-MFMA); Ps rows 8B-aligned -> 2x b64
            __builtin_amdgcn_s_setprio(1);
#pragma unroll
            for (int kc = 0; kc < 2; ++kc) {
                const uint2* pp = (const uint2*)(PsR + kc * 32 + l16 * 8);
                union { uint2 u2[2]; s16x8 v; } uu;
                uu.u2[0] = pp[0];
                uu.u2[1] = pp[1];
                s16x8 pa = uu.v;
                accL = mfma16(pa, ones, accL);
#pragma unroll
                for (int fd = 0; fd < 4; ++fd)
                    accO[fd] = mfma16(pa, ldfrag(Vs[cur], fd * 16 + l15, kc * 64 + l16 * 16),
                                      accO[fd]);
            }
            __builtin_amdgcn_s_setprio(0);

            __syncthreads();  // single barrier: drains prefetch, publishes all buffers
            cur ^= 1;
            rsb += 64;
            if (rsb == 192) rsb = 0;
        }

        // write attn_vec row-normalized, bf16, layout [i*4+b][n*64+d]
#pragma unroll
        for (int r = 0; r < 4; ++r) {
            float inv = 1.f / accL[r];
            int ig = i0 + wid * 16 + qr0 + r;
#pragma unroll
            for (int fd = 0; fd < 4; ++fd)
                av[((size_t)ig * 4 + b) * 1024 + n * 64 + fd * 16 + l15] = f2bf(accO[fd][r] * inv);
        }
    }
}

// ---------------------------------------------------------------- layernorm (in-place on d_out)
__global__ __launch_bounds__(256) void k_ln(float* __restrict__ y, const float* __restrict__ g,
                                            const float* __restrict__ bta) {
    int row = blockIdx.x, tid = threadIdx.x;
    int lane = tid & 63, wid = tid >> 6;
    float4 v = ((const float4*)(y + (size_t)row * 1024))[tid];
    float s = v.x + v.y + v.z + v.w;
    float sq = v.x * v.x + v.y * v.y + v.z * v.z + v.w * v.w;
#pragma unroll
    for (int msk = 1; msk <= 32; msk <<= 1) {
        s += __shfl_xor(s, msk, 64);
        sq += __shfl_xor(sq, msk, 64);
    }
    __shared__ float red[2][4];
    if (lane == 0) { red[0][wid] = s; red[1][wid] = sq; }
    __syncthreads();
    s = red[0][0] + red[0][1] + red[0][2] + red[0][3];
    sq = red[1][0] + red[1][1] + red[1][2] + red[1][3];
    float mu = s * (1.f / 1024.f);
    float var = sq * (1.f / 1024.f) - mu * mu;
    float rs = rsqrtf(var + 1e-5f);
    float4 gv = ((const float4*)g)[tid];
    float4 bv = ((const float4*)bta)[tid];
    float4 o;
    o.x = (v.x - mu) * rs * gv.x + bv.x;
    o.y = (v.y - mu) * rs * gv.y + bv.y;
    o.z = (v.z - mu) * rs * gv.z + bv.z;
    o.w = (v.w - mu) * rs * gv.w + bv.w;
    ((float4*)(y + (size_t)row * 1024))[tid] = o;
}

// ---------------------------------------------------------------- launch
extern "C" void kernel_launch(void* const* d_in, const int* in_sizes, int n_in,
                              void* d_out, int out_size, void* d_ws, size_t ws_size,
                              hipStream_t stream) {
    const float* w      = (const float*)d_in[0];
    const float* mems   = (const float*)d_in[1];
    const float* r_emb  = (const float*)d_in[2];
    const float* r_wb   = (const float*)d_in[3];
    const float* r_bias = (const float*)d_in[4];
    const float* Wqkv   = (const float*)d_in[5];
    const float* Wo     = (const float*)d_in[6];
    const float* ln_g   = (const float*)d_in[7];
    const float* ln_b   = (const float*)d_in[8];
    float* out = (float*)d_out;

    char* p = (char*)d_ws;
    auto alloc = [&](size_t bytes) {
        char* q = p;
        p += (bytes + 255) & ~(size_t)255;
        return q;
    };
    unsigned short* catb  = (unsigned short*)alloc(8192ull * 1024 * 2);      // 16 MB
    unsigned short* wqkvT = (unsigned short*)alloc(3072ull * 1024 * 2);      // 6 MB
    unsigned short* woT   = (unsigned short*)alloc(1024ull * 1024 * 2);      // 2 MB
    unsigned short* rb    = (unsigned short*)alloc(16ull * 2048 * 64 * 2);   // 4 MB
    float*          rbt   = (float*)alloc(16ull * 2048 * 4);                 // 128 KB
    unsigned short* qbuf  = (unsigned short*)alloc(64ull * 1024 * 64 * 2);   // 8 MB
    unsigned short* kbuf  = (unsigned short*)alloc(64ull * 2048 * 64 * 2);   // 16 MB
    unsigned short* vtb   = (unsigned short*)alloc(64ull * 2048 * 64 * 2);   // 16 MB (transposed V)
    unsigned short* av    = (unsigned short*)alloc(4096ull * 1024 * 2);      // 8 MB

    k_prep_all<<<5632, 256, 0, stream>>>(mems, w, r_emb, r_bias, Wqkv, Wo,
                                         catb, wqkvT, woT, rb, rbt);

    // GEMM1: 1280 blocks, dead-tile remap; V written transposed in-epilogue
    k_gemm<0><<<1280, 256, 0, stream>>>(catb, wqkvT, 1024, 3072,
                                        nullptr, nullptr, qbuf, kbuf, vtb);
    k_attn<<<dim3(8, 64), 256, 0, stream>>>(qbuf, kbuf, vtb, rb, rbt, r_wb, av);
    k_gemm<1><<<dim3(8, 32), 256, 0, stream>>>(av, woT, 1024, 1024,
                                               w, out, nullptr, nullptr, nullptr);
    k_ln<<<4096, 256, 0, stream>>>(out, ln_g, ln_b);
}

// Round 17
// 234.997 us; speedup vs baseline: 1.0920x; 1.0157x over previous
//
#include <hip/hip_runtime.h>
#include <hip/hip_bf16.h>
#include <stdint.h>

typedef __attribute__((ext_vector_type(8))) short s16x8;
typedef __attribute__((ext_vector_type(4))) float f32x4;

#define DEVFN static __device__ __forceinline__

DEVFN unsigned short f2bf(float f) {
    union { float f; uint32_t u; } v; v.f = f;
    uint32_t u = v.u;
    uint32_t r = (u + 0x7fffu + ((u >> 16) & 1u)) >> 16;
    return (unsigned short)r;
}
DEVFN float bf2f(unsigned short h) {
    union { uint32_t u; float f; } v; v.u = ((uint32_t)h) << 16;
    return v.f;
}
DEVFN float bfu_lo(uint32_t v) {
    union { uint32_t u; float f; } c; c.u = v << 16; return c.f;
}
DEVFN float bfu_hi(uint32_t v) {
    union { uint32_t u; float f; } c; c.u = v & 0xffff0000u; return c.f;
}
DEVFN uint32_t cvtpk(float lo, float hi) {
    uint32_t r;
    asm("v_cvt_pk_bf16_f32 %0, %1, %2" : "=v"(r) : "v"(lo), "v"(hi));
    return r;
}

DEVFN void gload16(const void* g, void* l) {
    __builtin_amdgcn_global_load_lds(
        (const __attribute__((address_space(1))) unsigned int*)(uintptr_t)g,
        (__attribute__((address_space(3))) unsigned int*)(uint32_t)(uintptr_t)l,
        16, 0, 0);
}

DEVFN f32x4 mfma16(s16x8 a, s16x8 b, f32x4 c) {
    return __builtin_amdgcn_mfma_f32_16x16x32_bf16(a, b, c, 0, 0, 0);
}

// swizzled fragment read: tile rows are 128 B; XOR row-bits into 16B-slot bits
DEVFN s16x8 ldfrag(const unsigned short* base, int row, int cb) {
    return *(const s16x8*)((const char*)base + row * 128 + (cb ^ ((row & 7) << 4)));
}

// ---------------------------------------------------------------- fused prep
//   [0,3072)    : Wqkv transpose-convert (fp32 [1024][3072] -> bf16 [3072][1024])
//   [3072,4096) : Wo transpose-convert   (fp32 [1024][1024] -> bf16 [1024][1024])
//   [4096,5120) : cat = [mems;w] fp32 -> bf16 (grid-stride)
//   [5120,5632) : r_emb remap -> rb [n][jj][d] bf16 ; r_bias -> rbt [n][jj] f32
__global__ __launch_bounds__(256) void k_prep_all(const float* __restrict__ mems,
                                                  const float* __restrict__ w,
                                                  const float* __restrict__ r_emb,
                                                  const float* __restrict__ r_bias,
                                                  const float* __restrict__ Wqkv,
                                                  const float* __restrict__ Wo,
                                                  unsigned short* __restrict__ catb,
                                                  unsigned short* __restrict__ wqkvT,
                                                  unsigned short* __restrict__ woT,
                                                  unsigned short* __restrict__ rb,
                                                  float* __restrict__ rbt) {
    __shared__ float T[32][33];
    int bid = blockIdx.x, tid = threadIdx.x;
    if (bid < 4096) {
        const float* in;
        unsigned short* out;
        int R = 1024, C;
        int c0, r0;
        if (bid < 3072) {
            in = Wqkv; out = wqkvT; C = 3072;
            c0 = (bid % 96) * 32; r0 = (bid / 96) * 32;
        } else {
            int b2 = bid - 3072;
            in = Wo; out = woT; C = 1024;
            c0 = (b2 & 31) * 32; r0 = (b2 >> 5) * 32;
        }
        int tx = tid & 31, ty = tid >> 5;
#pragma unroll
        for (int i = 0; i < 4; ++i) {
            int r = ty * 4 + i;
            T[r][tx] = in[(size_t)(r0 + r) * C + c0 + tx];
        }
        __syncthreads();
#pragma unroll
        for (int i = 0; i < 4; ++i) {
            int r = ty * 4 + i;
            out[(size_t)(c0 + r) * R + r0 + tx] = f2bf(T[tx][r]);
        }
    } else if (bid < 5120) {
        long long i0 = (long long)(bid - 4096) * 256 + tid;
        for (long long i = i0; i < 2097152; i += 262144) {
            float4 v = (i < 1048576) ? ((const float4*)mems)[i] : ((const float4*)w)[i - 1048576];
            ushort4 o = make_ushort4(f2bf(v.x), f2bf(v.y), f2bf(v.z), f2bf(v.w));
            ((ushort4*)catb)[i] = o;
        }
    } else {
        long long o0 = (long long)(bid - 5120) * 256 + tid;
        for (long long o = o0; o < 2097152; o += 131072) {
            int n = (int)(o >> 17);
            int jj = (int)((o >> 6) & 2047);
            int d = (int)(o & 63);
            rb[o] = f2bf(r_emb[((size_t)jj * 16 + n) * 64 + d]);
        }
        for (long long o = o0; o < 32768; o += 131072)
            rbt[o] = r_bias[(size_t)(o & 2047) * 16 + (o >> 11)];
    }
}

// ---------------------------------------------------------------- GEMM
// C = A(M x K, bf16 row-major) * B^T, B given transposed [N][K] bf16.
// 128x128 tile, BK=64, 4 waves (2x2), swizzled LDS.
// MODE 0 (QKV): 1D grid of 1280 blocks with dead-tile remap. V-tiles
//   (n0>=2048) transpose through the (dead) LDS in the epilogue and write
//   vt[bn][d][t] DIRECTLY (k_vtrans eliminated; vt must NOT alias catb).
// MODE 1 (out proj): 2D grid, epilogue adds residual.
template <int MODE>
__global__ __launch_bounds__(256) void k_gemm(const unsigned short* __restrict__ A,
                                              const unsigned short* __restrict__ B,
                                              int K, int N,
                                              const float* __restrict__ wres,
                                              float* __restrict__ outf,
                                              unsigned short* __restrict__ qb,
                                              unsigned short* __restrict__ kb,
                                              unsigned short* __restrict__ vtb) {
    __shared__ unsigned short smem[128 * 128];  // 32 KB: As | Bs ; reused by V-epilogue
    unsigned short* As = smem;
    unsigned short* Bs = smem + 8192;
    int tid = threadIdx.x, lane = tid & 63, wid = tid >> 6;
    int l15 = lane & 15, l16 = lane >> 4;
    int m0, n0;
    if (MODE == 0) {
        int bid = blockIdx.x;
        if (bid < 1024) {
            m0 = (bid >> 4) * 128;
            n0 = (8 + (bid & 15)) * 128;
        } else {
            int q = bid - 1024;
            m0 = (32 + (q >> 3)) * 128;
            n0 = (q & 7) * 128;
        }
    } else {
        m0 = blockIdx.y * 128;
        n0 = blockIdx.x * 128;
    }
    int wr = wid >> 1, wc = wid & 1;
    f32x4 acc[4][4];
#pragma unroll
    for (int a = 0; a < 4; ++a)
#pragma unroll
        for (int b = 0; b < 4; ++b) acc[a][b] = f32x4{0.f, 0.f, 0.f, 0.f};

    for (int k0 = 0; k0 < K; k0 += 64) {
        __syncthreads();
#pragma unroll
        for (int it = 0; it < 4; ++it) {
            int slot = it * 4 + wid;
            int elem = slot * 512 + lane * 8;
            int row = elem >> 6;
            int colb = (lane & 7) * 16;
            int scol = (colb ^ ((row & 7) << 4)) >> 1;
            gload16(A + (size_t)(m0 + row) * K + k0 + scol, (char*)As + (size_t)slot * 1024);
            gload16(B + (size_t)(n0 + row) * K + k0 + scol, (char*)Bs + (size_t)slot * 1024);
        }
        asm volatile("s_waitcnt vmcnt(0)" ::: "memory");
        __syncthreads();
#pragma unroll
        for (int kc = 0; kc < 2; ++kc) {
            s16x8 af[4], bfr[4];
#pragma unroll
            for (int f = 0; f < 4; ++f)
                af[f] = ldfrag(As, wr * 64 + f * 16 + l15, kc * 64 + l16 * 16);
#pragma unroll
            for (int f = 0; f < 4; ++f)
                bfr[f] = ldfrag(Bs, wc * 64 + f * 16 + l15, kc * 64 + l16 * 16);
#pragma unroll
            for (int fm = 0; fm < 4; ++fm)
#pragma unroll
                for (int fn = 0; fn < 4; ++fn)
                    acc[fm][fn] = mfma16(af[fm], bfr[fn], acc[fm][fn]);
        }
    }

    if (MODE == 0 && n0 >= 2048) {
        // ---- V-tile epilogue: LDS transpose -> vt[bn][d][t] direct ----
        int nnBase = (n0 - 2048) >> 6;
        int tB = m0 >> 2;
#pragma unroll
        for (int half = 0; half < 2; ++half) {
            __syncthreads();  // LDS (As/Bs or prior half) fully consumed
            if (wc == half) {
#pragma unroll
                for (int fn = 0; fn < 4; ++fn) {
                    int cl = fn * 16 + l15;  // 0..63
#pragma unroll
                    for (int fm = 0; fm < 4; ++fm) {
                        int tl = wr * 16 + fm * 4 + l16;  // 0..31
#pragma unroll
                        for (int r = 0; r < 4; ++r)
                            smem[cl * 136 + r * 32 + tl] = f2bf(acc[fm][fn][r]);
                    }
                }
            }
            __syncthreads();
            int cl = tid & 63, bb = tid >> 6;  // one (d, batch) task per thread
            const unsigned short* src = &smem[cl * 136 + bb * 32];
            s16x8 v0 = *(const s16x8*)src;
            s16x8 v1 = *(const s16x8*)(src + 8);
            s16x8 v2 = *(const s16x8*)(src + 16);
            s16x8 v3 = *(const s16x8*)(src + 24);
            unsigned short* dst = vtb + (size_t)(bb * 16 + nnBase + half) * 131072 +
                                  (size_t)cl * 2048 + tB;
            *(s16x8*)dst = v0;
            *(s16x8*)(dst + 8) = v1;
            *(s16x8*)(dst + 16) = v2;
            *(s16x8*)(dst + 24) = v3;
        }
        return;
    }

#pragma unroll
    for (int fm = 0; fm < 4; ++fm)
#pragma unroll
        for (int fn = 0; fn < 4; ++fn)
#pragma unroll
            for (int r = 0; r < 4; ++r) {
                int row = m0 + wr * 64 + fm * 16 + l16 * 4 + r;
                int col = n0 + wc * 64 + fn * 16 + l15;
                float v = acc[fm][fn][r];
                if (MODE == 0) {
                    int t = row >> 2, bb = row & 3;
                    if (col < 1024) {
                        if (t >= 1024) {
                            int nn = col >> 6, d = col & 63;
                            qb[((size_t)(bb * 16 + nn) * 1024 + (t - 1024)) * 64 + d] = f2bf(v);
                        }
                    } else {
                        int c2 = col - 1024, nn = c2 >> 6, d = c2 & 63;
                        kb[((size_t)(bb * 16 + nn) * 2048 + t) * 64 + d] = f2bf(v);
                    }
                } else {
                    size_t o = (size_t)row * N + col;
                    outf[o] = v + wres[o];
                }
            }
}

// ---------------------------------------------------------------- attention
// r16 structure + XCD-aware block remap (T1): flat id f = by*8+bx (x fastest,
// XCD = f%8 round-robin). bn = (f&7)*8 + (f>>3)&7 makes all 8 blocks sharing
// one bn's K/V/rb land on ONE XCD L2 (bijective). bx2 = f>>6 selects the
// i-tile pair. Everything else byte-identical to r16 (132.4 us measured).
__global__ __launch_bounds__(256) void k_attn(const unsigned short* __restrict__ qb,
                                              const unsigned short* __restrict__ kb,
                                              const unsigned short* __restrict__ vt,
                                              const unsigned short* __restrict__ rb,
                                              const float* __restrict__ rbt,
                                              const float* __restrict__ r_w_bias,
                                              unsigned short* __restrict__ av) {
    __shared__ unsigned short Ks[2][4096];   // [buf][jf][d] swizzled   16 KB
    __shared__ unsigned short Vs[2][4096];   // [buf][d][jf] swizzled   16 KB
    __shared__ unsigned short Rs[192 * 64];  // tri-buffer, swizzled    24 KB
    __shared__ unsigned short Elp[4][1920];  // El pool (Ps aliased)    15 KB
    __shared__ float rbs[192];               // tri-buffer band bias   .75 KB

    const float SC = 0.18033688f;  // 0.125 * log2(e)
    int tid = threadIdx.x, lane = tid & 63, wid = tid >> 6;
    int l15 = lane & 15, l16 = lane >> 4;
    int qr0 = l16 * 4;
    // XCD-aware remap: f%8 = XCD; same-bn blocks share an XCD L2
    int f = (int)blockIdx.y * 8 + (int)blockIdx.x;
    int bn = ((f & 7) << 3) | ((f >> 3) & 7);
    int bx2 = f >> 6;
    int b = bn >> 4, n = bn & 15;
    size_t bq = (size_t)bn * 65536;
    size_t bk = (size_t)bn * 131072;
    int rbase = 48 - wid * 16;              // wave band-window start offset
    int lrow = lane >> 3;                   // dest row within an 8-row group
    int colb = (lane & 7) * 16;             // dest byte col
    int scolE = (colb ^ (lrow << 4)) >> 1;  // swizzled source col (elements)

    // loop-invariant LDS addresses (all further offsets are immediates)
    unsigned short* ElW = &Elp[wid][20 * l15 + 21 * qr0];          // + fe*320 + r*21
    const unsigned short* ElR = &Elp[wid][20 * (l15 + 15) + qr0];  // + fn*320, b64
    unsigned short* PsW = &Elp[wid][qr0 * 68 + l15];               // + fn*16 + r*68
    const unsigned short* PsR = &Elp[wid][l15 * 68];               // + kc*32 + l16*8

    s16x8 ones;
#pragma unroll
    for (int t = 0; t < 8; ++t) ones[t] = (short)0x3F80;  // bf16 1.0

    for (int h = 0; h < 2; ++h) {
        int it8 = h ? 15 - bx2 : bx2;
        int i0 = it8 * 64;
        int njt = it8 + 17;
        int jjb = 960 - i0;  // band base: jj = jjb + j0 + rbase + bcol

        // Q fragments (pre-scaled by SC)
        s16x8 aq[2], aqr[2];
        {
            int qrow = i0 + wid * 16 + l15;
#pragma unroll
            for (int kc = 0; kc < 2; ++kc) {
                s16x8 qv = *(const s16x8*)(qb + bq + (size_t)qrow * 64 + kc * 32 + l16 * 8);
                s16x8 q1, q2;
#pragma unroll
                for (int t = 0; t < 8; ++t) {
                    float ff = bf2f((unsigned short)qv[t]);
                    float rw = r_w_bias[n * 64 + kc * 32 + l16 * 8 + t];
                    q1[t] = (short)f2bf(ff * SC);
                    q2[t] = (short)f2bf((ff + rw) * SC);
                }
                aq[kc] = q1;
                aqr[kc] = q2;
            }
        }

        float m_[4];
        f32x4 accO[4], accL;
#pragma unroll
        for (int r = 0; r < 4; ++r) m_[r] = -3.0e38f;
#pragma unroll
        for (int ff = 0; ff < 4; ++ff) accO[ff] = f32x4{0.f, 0.f, 0.f, 0.f};
        accL = f32x4{0.f, 0.f, 0.f, 0.f};

        // ---- prologue: K/V tile 0, R band rows [0,128), rbs ----
#pragma unroll
        for (int q = 0; q < 2; ++q) {
            int s = wid * 2 + q;
            int row = s * 8 + lrow;
            gload16(kb + bk + (size_t)row * 64 + scolE, (char*)Ks[0] + s * 1024);
            gload16(vt + bk + (size_t)row * 2048 + scolE, (char*)Vs[0] + s * 1024);
        }
#pragma unroll
        for (int q = 0; q < 4; ++q) {
            int s = wid * 4 + q;
            int jju = jjb + s * 8 + lrow;  // <= 1087, no clamp needed
            gload16(rb + (size_t)n * 131072 + (size_t)jju * 64 + scolE,
                    (char*)Rs + (s * 8) * 128);
        }
        if (tid < 128) {
            int jju = jjb + tid;
            rbs[tid] = SC * rbt[(size_t)n * 2048 + jju];
        }
        __syncthreads();

        int cur = 0, rsb = 0;
        for (int jt = 0; jt < njt; ++jt) {
            int j0 = jt * 64;
            int jjc = jjb + j0;
            bool pf = (jt + 1 < njt);

            // E = q . R_window^T (16x80/wave) -> skewed El, rbias+mask folded
            __builtin_amdgcn_s_setprio(1);
#pragma unroll
            for (int fe = 0; fe < 5; ++fe) {
                int row = rsb + rbase + fe * 16 + l15;
                if (row >= 192) row -= 192;
                f32x4 e = f32x4{0.f, 0.f, 0.f, 0.f};
                e = mfma16(aq[0], ldfrag(Rs, row, l16 * 16), e);
                e = mfma16(aq[1], ldfrag(Rs, row, 64 + l16 * 16), e);
                float rbv = rbs[row];
                uint32_t p01 = cvtpk(e[0] + rbv, e[1] + rbv);
                uint32_t p23 = cvtpk(e[2] + rbv, e[3] + rbv);
                ElW[fe * 320] = (unsigned short)p01;
                ElW[fe * 320 + 21] = (unsigned short)(p01 >> 16);
                ElW[fe * 320 + 42] = (unsigned short)p23;
                ElW[fe * 320 + 63] = (unsigned short)(p23 >> 16);
            }
            // AC = (q + r_w_bias) . K^T
            f32x4 sAC[4];
#pragma unroll
            for (int fn = 0; fn < 4; ++fn) {
                f32x4 a = f32x4{0.f, 0.f, 0.f, 0.f};
#pragma unroll
                for (int kc = 0; kc < 2; ++kc)
                    a = mfma16(aqr[kc], ldfrag(Ks[cur], fn * 16 + l15, kc * 64 + l16 * 16), a);
                sAC[fn] = a;
            }
            __builtin_amdgcn_s_setprio(0);

            // prefetch issue (flies under softmax + PV + barrier)
            if (pf) {
                int j0n = j0 + 64;
#pragma unroll
                for (int q = 0; q < 2; ++q) {
                    int s = wid * 2 + q;
                    int row = s * 8 + lrow;
                    gload16(kb + bk + (size_t)(j0n + row) * 64 + scolE,
                            (char*)Ks[cur ^ 1] + s * 1024);
                    gload16(vt + bk + (size_t)row * 2048 + j0n + scolE,
                            (char*)Vs[cur ^ 1] + s * 1024);
                }
#pragma unroll
                for (int q = 0; q < 2; ++q) {
                    int s = wid * 2 + q;
                    int w = rsb + 128 + s * 8;
                    if (w >= 192) w -= 192;
                    int jju = jjc + 128 + s * 8 + lrow;
                    int jja = jju > 2047 ? 2047 : jju;  // clamp source only
                    gload16(rb + (size_t)n * 131072 + (size_t)jja * 64 + scolE,
                            (char*)Rs + w * 128);
                }
                if (tid < 64) {
                    int w = rsb + 128 + tid;
                    if (w >= 192) w -= 192;
                    int jju = jjc + 128 + tid;
                    rbs[w] = (jju <= 2047) ? SC * rbt[(size_t)n * 2048 + jju] : -1.0e30f;
                }
            }

            // softmax: scores via 4x b64 diagonal reads; defer-max THR=8
            float pe[4][4];
            float lmax[4] = {-3.0e38f, -3.0e38f, -3.0e38f, -3.0e38f};
#pragma unroll
            for (int fn = 0; fn < 4; ++fn) {
                uint2 ev = *(const uint2*)(ElR + fn * 320);
                pe[fn][0] = sAC[fn][0] + bfu_lo(ev.x);
                pe[fn][1] = sAC[fn][1] + bfu_hi(ev.x);
                pe[fn][2] = sAC[fn][2] + bfu_lo(ev.y);
                pe[fn][3] = sAC[fn][3] + bfu_hi(ev.y);
#pragma unroll
                for (int r = 0; r < 4; ++r) lmax[r] = fmaxf(lmax[r], pe[fn][r]);
            }
            bool need = (lmax[0] > m_[0] + 8.f) | (lmax[1] > m_[1] + 8.f) |
                        (lmax[2] > m_[2] + 8.f) | (lmax[3] > m_[3] + 8.f);
            if (__any(need)) {
#pragma unroll
                for (int msk = 1; msk <= 8; msk <<= 1)
#pragma unroll
                    for (int r = 0; r < 4; ++r)
                        lmax[r] = fmaxf(lmax[r], __shfl_xor(lmax[r], msk, 64));
#pragma unroll
                for (int r = 0; r < 4; ++r) {
                    float mn = fmaxf(m_[r], lmax[r]);
                    float alpha = __builtin_exp2f(m_[r] - mn);
                    m_[r] = mn;
                    accL[r] *= alpha;
#pragma unroll
                    for (int ff = 0; ff < 4; ++ff) accO[ff][r] *= alpha;
                }
            }
            // all El reads above complete before these aliased Ps writes
#pragma unroll
            for (int fn = 0; fn < 4; ++fn) {
                float e0 = __builtin_exp2f(pe[fn][0] - m_[0]);
                float e1 = __builtin_exp2f(pe[fn][1] - m_[1]);
                float e2 = __builtin_exp2f(pe[fn][2] - m_[2]);
                float e3 = __builtin_exp2f(pe[fn][3] - m_[3]);
                uint32_t a = cvtpk(e0, e1);
                uint32_t c = cvtpk(e2, e3);
                PsW[fn * 16] = (unsigned short)a;
                PsW[fn * 16 + 68] = (unsigned short)(a >> 16);
                PsW[fn * 16 + 136] = (unsigned short)c;
                PsW[fn * 16 + 204] = (unsigned short)(c >> 16);
            }

            // PV (+ row-sum via ones-MFMA); Ps rows 8B-aligned -> 2x b64
            __builtin_amdgcn_s_setprio(1);
#pragma unroll
            for (int kc = 0; kc < 2; ++kc) {
                const uint2* pp = (const uint2*)(PsR + kc * 32 + l16 * 8);
                union { uint2 u2[2]; s16x8 v; } uu;
                uu.u2[0] = pp[0];
                uu.u2[1] = pp[1];
                s16x8 pa = uu.v;
                accL = mfma16(pa, ones, accL);
#pragma unroll
                for (int fd = 0; fd < 4; ++fd)
                    accO[fd] = mfma16(pa, ldfrag(Vs[cur], fd * 16 + l15, kc * 64 + l16 * 16),
                                      accO[fd]);
            }
            __builtin_amdgcn_s_setprio(0);

            __syncthreads();  // single barrier: drains prefetch, publishes all buffers
            cur ^= 1;
            rsb += 64;
            if (rsb == 192) rsb = 0;
        }

        // write attn_vec row-normalized, bf16, layout [i*4+b][n*64+d]
#pragma unroll
        for (int r = 0; r < 4; ++r) {
            float inv = 1.f / accL[r];
            int ig = i0 + wid * 16 + qr0 + r;
#pragma unroll
            for (int fd = 0; fd < 4; ++fd)
                av[((size_t)ig * 4 + b) * 1024 + n * 64 + fd * 16 + l15] = f2bf(accO[fd][r] * inv);
        }
    }
}

// ---------------------------------------------------------------- layernorm (in-place on d_out)
__global__ __launch_bounds__(256) void k_ln(float* __restrict__ y, const float* __restrict__ g,
                                            const float* __restrict__ bta) {
    int row = blockIdx.x, tid = threadIdx.x;
    int lane = tid & 63, wid = tid >> 6;
    float4 v = ((const float4*)(y + (size_t)row * 1024))[tid];
    float s = v.x + v.y + v.z + v.w;
    float sq = v.x * v.x + v.y * v.y + v.z * v.z + v.w * v.w;
#pragma unroll
    for (int msk = 1; msk <= 32; msk <<= 1) {
        s += __shfl_xor(s, msk, 64);
        sq += __shfl_xor(sq, msk, 64);
    }
    __shared__ float red[2][4];
    if (lane == 0) { red[0][wid] = s; red[1][wid] = sq; }
    __syncthreads();
    s = red[0][0] + red[0][1] + red[0][2] + red[0][3];
    sq = red[1][0] + red[1][1] + red[1][2] + red[1][3];
    float mu = s * (1.f / 1024.f);
    float var = sq * (1.f / 1024.f) - mu * mu;
    float rs = rsqrtf(var + 1e-5f);
    float4 gv = ((const float4*)g)[tid];
    float4 bv = ((const float4*)bta)[tid];
    float4 o;
    o.x = (v.x - mu) * rs * gv.x + bv.x;
    o.y = (v.y - mu) * rs * gv.y + bv.y;
    o.z = (v.z - mu) * rs * gv.z + bv.z;
    o.w = (v.w - mu) * rs * gv.w + bv.w;
    ((float4*)(y + (size_t)row * 1024))[tid] = o;
}

// ---------------------------------------------------------------- launch
extern "C" void kernel_launch(void* const* d_in, const int* in_sizes, int n_in,
                              void* d_out, int out_size, void* d_ws, size_t ws_size,
                              hipStream_t stream) {
    const float* w      = (const float*)d_in[0];
    const float* mems   = (const float*)d_in[1];
    const float* r_emb  = (const float*)d_in[2];
    const float* r_wb   = (const float*)d_in[3];
    const float* r_bias = (const float*)d_in[4];
    const float* Wqkv   = (const float*)d_in[5];
    const float* Wo     = (const float*)d_in[6];
    const float* ln_g   = (const float*)d_in[7];
    const float* ln_b   = (const float*)d_in[8];
    float* out = (float*)d_out;

    char* p = (char*)d_ws;
    auto alloc = [&](size_t bytes) {
        char* q = p;
        p += (bytes + 255) & ~(size_t)255;
        return q;
    };
    unsigned short* catb  = (unsigned short*)alloc(8192ull * 1024 * 2);      // 16 MB
    unsigned short* wqkvT = (unsigned short*)alloc(3072ull * 1024 * 2);      // 6 MB
    unsigned short* woT   = (unsigned short*)alloc(1024ull * 1024 * 2);      // 2 MB
    unsigned short* rb    = (unsigned short*)alloc(16ull * 2048 * 64 * 2);   // 4 MB
    float*          rbt   = (float*)alloc(16ull * 2048 * 4);                 // 128 KB
    unsigned short* qbuf  = (unsigned short*)alloc(64ull * 1024 * 64 * 2);   // 8 MB
    unsigned short* kbuf  = (unsigned short*)alloc(64ull * 2048 * 64 * 2);   // 16 MB
    unsigned short* vtb   = (unsigned short*)alloc(64ull * 2048 * 64 * 2);   // 16 MB (transposed V)
    unsigned short* av    = (unsigned short*)alloc(4096ull * 1024 * 2);      // 8 MB

    k_prep_all<<<5632, 256, 0, stream>>>(mems, w, r_emb, r_bias, Wqkv, Wo,
                                         catb, wqkvT, woT, rb, rbt);

    // GEMM1: 1280 blocks, dead-tile remap; V written transposed in-epilogue
    k_gemm<0><<<1280, 256, 0, stream>>>(catb, wqkvT, 1024, 3072,
                                        nullptr, nullptr, qbuf, kbuf, vtb);
    k_attn<<<dim3(8, 64), 256, 0, stream>>>(qbuf, kbuf, vtb, rb, rbt, r_wb, av);
    k_gemm<1><<<dim3(8, 32), 256, 0, stream>>>(av, woT, 1024, 1024,
                                               w, out, nullptr, nullptr, nullptr);
    k_ln<<<4096, 256, 0, stream>>>(out, ln_g, ln_b);
}

// Round 18
// 229.307 us; speedup vs baseline: 1.1191x; 1.0248x over previous
//
#include <hip/hip_runtime.h>
#include <hip/hip_bf16.h>
#include <stdint.h>

typedef __attribute__((ext_vector_type(8))) short s16x8;
typedef __attribute__((ext_vector_type(4))) float f32x4;

#define DEVFN static __device__ __forceinline__

DEVFN unsigned short f2bf(float f) {
    union { float f; uint32_t u; } v; v.f = f;
    uint32_t u = v.u;
    uint32_t r = (u + 0x7fffu + ((u >> 16) & 1u)) >> 16;
    return (unsigned short)r;
}
DEVFN float bf2f(unsigned short h) {
    union { uint32_t u; float f; } v; v.u = ((uint32_t)h) << 16;
    return v.f;
}
DEVFN float bfu_lo(uint32_t v) {
    union { uint32_t u; float f; } c; c.u = v << 16; return c.f;
}
DEVFN float bfu_hi(uint32_t v) {
    union { uint32_t u; float f; } c; c.u = v & 0xffff0000u; return c.f;
}
DEVFN uint32_t cvtpk(float lo, float hi) {
    uint32_t r;
    asm("v_cvt_pk_bf16_f32 %0, %1, %2" : "=v"(r) : "v"(lo), "v"(hi));
    return r;
}

DEVFN void gload16(const void* g, void* l) {
    __builtin_amdgcn_global_load_lds(
        (const __attribute__((address_space(1))) unsigned int*)(uintptr_t)g,
        (__attribute__((address_space(3))) unsigned int*)(uint32_t)(uintptr_t)l,
        16, 0, 0);
}

DEVFN f32x4 mfma16(s16x8 a, s16x8 b, f32x4 c) {
    return __builtin_amdgcn_mfma_f32_16x16x32_bf16(a, b, c, 0, 0, 0);
}

// swizzled fragment read: tile rows are 128 B; XOR row-bits into 16B-slot bits
DEVFN s16x8 ldfrag(const unsigned short* base, int row, int cb) {
    return *(const s16x8*)((const char*)base + row * 128 + (cb ^ ((row & 7) << 4)));
}

// ---------------------------------------------------------------- fused prep
//   [0,3072)    : Wqkv transpose-convert (fp32 [1024][3072] -> bf16 [3072][1024])
//   [3072,4096) : Wo transpose-convert   (fp32 [1024][1024] -> bf16 [1024][1024])
//   [4096,5120) : cat = [mems;w] fp32 -> bf16 (grid-stride)
//   [5120,5632) : r_emb remap -> rb [n][jj][d] bf16 ; r_bias -> rbt [n][jj] f32
__global__ __launch_bounds__(256) void k_prep_all(const float* __restrict__ mems,
                                                  const float* __restrict__ w,
                                                  const float* __restrict__ r_emb,
                                                  const float* __restrict__ r_bias,
                                                  const float* __restrict__ Wqkv,
                                                  const float* __restrict__ Wo,
                                                  unsigned short* __restrict__ catb,
                                                  unsigned short* __restrict__ wqkvT,
                                                  unsigned short* __restrict__ woT,
                                                  unsigned short* __restrict__ rb,
                                                  float* __restrict__ rbt) {
    __shared__ float T[32][33];
    int bid = blockIdx.x, tid = threadIdx.x;
    if (bid < 4096) {
        const float* in;
        unsigned short* out;
        int R = 1024, C;
        int c0, r0;
        if (bid < 3072) {
            in = Wqkv; out = wqkvT; C = 3072;
            c0 = (bid % 96) * 32; r0 = (bid / 96) * 32;
        } else {
            int b2 = bid - 3072;
            in = Wo; out = woT; C = 1024;
            c0 = (b2 & 31) * 32; r0 = (b2 >> 5) * 32;
        }
        int tx = tid & 31, ty = tid >> 5;
#pragma unroll
        for (int i = 0; i < 4; ++i) {
            int r = ty * 4 + i;
            T[r][tx] = in[(size_t)(r0 + r) * C + c0 + tx];
        }
        __syncthreads();
#pragma unroll
        for (int i = 0; i < 4; ++i) {
            int r = ty * 4 + i;
            out[(size_t)(c0 + r) * R + r0 + tx] = f2bf(T[tx][r]);
        }
    } else if (bid < 5120) {
        long long i0 = (long long)(bid - 4096) * 256 + tid;
        for (long long i = i0; i < 2097152; i += 262144) {
            float4 v = (i < 1048576) ? ((const float4*)mems)[i] : ((const float4*)w)[i - 1048576];
            ushort4 o = make_ushort4(f2bf(v.x), f2bf(v.y), f2bf(v.z), f2bf(v.w));
            ((ushort4*)catb)[i] = o;
        }
    } else {
        long long o0 = (long long)(bid - 5120) * 256 + tid;
        for (long long o = o0; o < 2097152; o += 131072) {
            int n = (int)(o >> 17);
            int jj = (int)((o >> 6) & 2047);
            int d = (int)(o & 63);
            rb[o] = f2bf(r_emb[((size_t)jj * 16 + n) * 64 + d]);
        }
        for (long long o = o0; o < 32768; o += 131072)
            rbt[o] = r_bias[(size_t)(o & 2047) * 16 + (o >> 11)];
    }
}

// ---------------------------------------------------------------- GEMM1 (QKV)
// 1D grid of 1280 blocks with dead-tile remap. V-tiles (n0>=2048) transpose
// through the (dead) LDS in the epilogue and write vt[bn][d][t] directly.
__global__ __launch_bounds__(256) void k_gemm_qkv(const unsigned short* __restrict__ A,
                                                  const unsigned short* __restrict__ B,
                                                  unsigned short* __restrict__ qb,
                                                  unsigned short* __restrict__ kb,
                                                  unsigned short* __restrict__ vtb) {
    __shared__ unsigned short smem[128 * 128];  // 32 KB: As | Bs ; reused by V-epilogue
    unsigned short* As = smem;
    unsigned short* Bs = smem + 8192;
    const int K = 1024;
    int tid = threadIdx.x, lane = tid & 63, wid = tid >> 6;
    int l15 = lane & 15, l16 = lane >> 4;
    int m0, n0;
    {
        int bid = blockIdx.x;
        if (bid < 1024) {
            m0 = (bid >> 4) * 128;
            n0 = (8 + (bid & 15)) * 128;
        } else {
            int q = bid - 1024;
            m0 = (32 + (q >> 3)) * 128;
            n0 = (q & 7) * 128;
        }
    }
    int wr = wid >> 1, wc = wid & 1;
    f32x4 acc[4][4];
#pragma unroll
    for (int a = 0; a < 4; ++a)
#pragma unroll
        for (int b = 0; b < 4; ++b) acc[a][b] = f32x4{0.f, 0.f, 0.f, 0.f};

    for (int k0 = 0; k0 < K; k0 += 64) {
        __syncthreads();
#pragma unroll
        for (int it = 0; it < 4; ++it) {
            int slot = it * 4 + wid;
            int elem = slot * 512 + lane * 8;
            int row = elem >> 6;
            int colb = (lane & 7) * 16;
            int scol = (colb ^ ((row & 7) << 4)) >> 1;
            gload16(A + (size_t)(m0 + row) * K + k0 + scol, (char*)As + (size_t)slot * 1024);
            gload16(B + (size_t)(n0 + row) * K + k0 + scol, (char*)Bs + (size_t)slot * 1024);
        }
        asm volatile("s_waitcnt vmcnt(0)" ::: "memory");
        __syncthreads();
#pragma unroll
        for (int kc = 0; kc < 2; ++kc) {
            s16x8 af[4], bfr[4];
#pragma unroll
            for (int f = 0; f < 4; ++f)
                af[f] = ldfrag(As, wr * 64 + f * 16 + l15, kc * 64 + l16 * 16);
#pragma unroll
            for (int f = 0; f < 4; ++f)
                bfr[f] = ldfrag(Bs, wc * 64 + f * 16 + l15, kc * 64 + l16 * 16);
#pragma unroll
            for (int fm = 0; fm < 4; ++fm)
#pragma unroll
                for (int fn = 0; fn < 4; ++fn)
                    acc[fm][fn] = mfma16(af[fm], bfr[fn], acc[fm][fn]);
        }
    }

    if (n0 >= 2048) {
        // ---- V-tile epilogue: LDS transpose -> vt[bn][d][t] direct ----
        int nnBase = (n0 - 2048) >> 6;
        int tB = m0 >> 2;
#pragma unroll
        for (int half = 0; half < 2; ++half) {
            __syncthreads();  // LDS (As/Bs or prior half) fully consumed
            if (wc == half) {
#pragma unroll
                for (int fn = 0; fn < 4; ++fn) {
                    int cl = fn * 16 + l15;  // 0..63
#pragma unroll
                    for (int fm = 0; fm < 4; ++fm) {
                        int tl = wr * 16 + fm * 4 + l16;  // 0..31
#pragma unroll
                        for (int r = 0; r < 4; ++r)
                            smem[cl * 136 + r * 32 + tl] = f2bf(acc[fm][fn][r]);
                    }
                }
            }
            __syncthreads();
            int cl = tid & 63, bb = tid >> 6;  // one (d, batch) task per thread
            const unsigned short* src = &smem[cl * 136 + bb * 32];
            s16x8 v0 = *(const s16x8*)src;
            s16x8 v1 = *(const s16x8*)(src + 8);
            s16x8 v2 = *(const s16x8*)(src + 16);
            s16x8 v3 = *(const s16x8*)(src + 24);
            unsigned short* dst = vtb + (size_t)(bb * 16 + nnBase + half) * 131072 +
                                  (size_t)cl * 2048 + tB;
            *(s16x8*)dst = v0;
            *(s16x8*)(dst + 8) = v1;
            *(s16x8*)(dst + 16) = v2;
            *(s16x8*)(dst + 24) = v3;
        }
        return;
    }

#pragma unroll
    for (int fm = 0; fm < 4; ++fm)
#pragma unroll
        for (int fn = 0; fn < 4; ++fn)
#pragma unroll
            for (int r = 0; r < 4; ++r) {
                int row = m0 + wr * 64 + fm * 16 + l16 * 4 + r;
                int col = n0 + wc * 64 + fn * 16 + l15;
                float v = acc[fm][fn][r];
                int t = row >> 2, bb = row & 3;
                if (col < 1024) {
                    if (t >= 1024) {
                        int nn = col >> 6, d = col & 63;
                        qb[((size_t)(bb * 16 + nn) * 1024 + (t - 1024)) * 64 + d] = f2bf(v);
                    }
                } else {
                    int c2 = col - 1024, nn = c2 >> 6, d = c2 & 63;
                    kb[((size_t)(bb * 16 + nn) * 2048 + t) * 64 + d] = f2bf(v);
                }
            }
}

// ---------------------------------------------------------------- GEMM2 (out proj + residual)
// 64x128 tile, grid (8,64) = 512 blocks -> 2 blocks/CU (TLP to hide the
// vmcnt(0)+barrier staging drains; old 128x128/256-block version was 1/CU).
__global__ __launch_bounds__(256) void k_gemm_out(const unsigned short* __restrict__ A,
                                                  const unsigned short* __restrict__ B,
                                                  const float* __restrict__ wres,
                                                  float* __restrict__ outf) {
    __shared__ unsigned short As[64 * 64];    // 8 KB
    __shared__ unsigned short Bs[128 * 64];   // 16 KB
    const int K = 1024, N = 1024;
    int tid = threadIdx.x, lane = tid & 63, wid = tid >> 6;
    int l15 = lane & 15, l16 = lane >> 4;
    int m0 = blockIdx.y * 64, n0 = blockIdx.x * 128;
    int wr = wid >> 1, wc = wid & 1;  // wave = rows [wr*32,+32) x cols [wc*64,+64)
    f32x4 acc[2][4];
#pragma unroll
    for (int a = 0; a < 2; ++a)
#pragma unroll
        for (int b = 0; b < 4; ++b) acc[a][b] = f32x4{0.f, 0.f, 0.f, 0.f};

    for (int k0 = 0; k0 < K; k0 += 64) {
        __syncthreads();
#pragma unroll
        for (int it = 0; it < 6; ++it) {
            int slot = it * 4 + wid;  // 0..23 ; 0-7 -> As, 8-23 -> Bs
            int colb = (lane & 7) * 16;
            if (slot < 8) {
                int elem = slot * 512 + lane * 8;
                int row = elem >> 6;
                int scol = (colb ^ ((row & 7) << 4)) >> 1;
                gload16(A + (size_t)(m0 + row) * K + k0 + scol, (char*)As + (size_t)slot * 1024);
            } else {
                int s2 = slot - 8;
                int elem = s2 * 512 + lane * 8;
                int row = elem >> 6;
                int scol = (colb ^ ((row & 7) << 4)) >> 1;
                gload16(B + (size_t)(n0 + row) * K + k0 + scol, (char*)Bs + (size_t)s2 * 1024);
            }
        }
        asm volatile("s_waitcnt vmcnt(0)" ::: "memory");
        __syncthreads();
#pragma unroll
        for (int kc = 0; kc < 2; ++kc) {
            s16x8 af[2], bfr[4];
#pragma unroll
            for (int f = 0; f < 2; ++f)
                af[f] = ldfrag(As, wr * 32 + f * 16 + l15, kc * 64 + l16 * 16);
#pragma unroll
            for (int f = 0; f < 4; ++f)
                bfr[f] = ldfrag(Bs, wc * 64 + f * 16 + l15, kc * 64 + l16 * 16);
#pragma unroll
            for (int fm = 0; fm < 2; ++fm)
#pragma unroll
                for (int fn = 0; fn < 4; ++fn)
                    acc[fm][fn] = mfma16(af[fm], bfr[fn], acc[fm][fn]);
        }
    }
#pragma unroll
    for (int fm = 0; fm < 2; ++fm)
#pragma unroll
        for (int fn = 0; fn < 4; ++fn)
#pragma unroll
            for (int r = 0; r < 4; ++r) {
                int row = m0 + wr * 32 + fm * 16 + l16 * 4 + r;
                int col = n0 + wc * 64 + fn * 16 + l15;
                size_t o = (size_t)row * N + col;
                outf[o] = acc[fm][fn][r] + wres[o];
            }
}

// ---------------------------------------------------------------- attention
// r17 (best measured 127.1 us): paired i-tiles, tri-buffer Rs, single
// barrier, skewed El (stride 20), Ps aliased (stride 68), ls via ones-MFMA,
// T13 defer-max THR=8, prefetch AFTER AC, XCD-aware bn remap (T1).
__global__ __launch_bounds__(256) void k_attn(const unsigned short* __restrict__ qb,
                                              const unsigned short* __restrict__ kb,
                                              const unsigned short* __restrict__ vt,
                                              const unsigned short* __restrict__ rb,
                                              const float* __restrict__ rbt,
                                              const float* __restrict__ r_w_bias,
                                              unsigned short* __restrict__ av) {
    __shared__ unsigned short Ks[2][4096];   // [buf][jf][d] swizzled   16 KB
    __shared__ unsigned short Vs[2][4096];   // [buf][d][jf] swizzled   16 KB
    __shared__ unsigned short Rs[192 * 64];  // tri-buffer, swizzled    24 KB
    __shared__ unsigned short Elp[4][1920];  // El pool (Ps aliased)    15 KB
    __shared__ float rbs[192];               // tri-buffer band bias   .75 KB

    const float SC = 0.18033688f;  // 0.125 * log2(e)
    int tid = threadIdx.x, lane = tid & 63, wid = tid >> 6;
    int l15 = lane & 15, l16 = lane >> 4;
    int qr0 = l16 * 4;
    // XCD-aware remap: f%8 = XCD; same-bn blocks share an XCD L2
    int f = (int)blockIdx.y * 8 + (int)blockIdx.x;
    int bn = ((f & 7) << 3) | ((f >> 3) & 7);
    int bx2 = f >> 6;
    int b = bn >> 4, n = bn & 15;
    size_t bq = (size_t)bn * 65536;
    size_t bk = (size_t)bn * 131072;
    int rbase = 48 - wid * 16;              // wave band-window start offset
    int lrow = lane >> 3;                   // dest row within an 8-row group
    int colb = (lane & 7) * 16;             // dest byte col
    int scolE = (colb ^ (lrow << 4)) >> 1;  // swizzled source col (elements)

    // loop-invariant LDS addresses (all further offsets are immediates)
    unsigned short* ElW = &Elp[wid][20 * l15 + 21 * qr0];          // + fe*320 + r*21
    const unsigned short* ElR = &Elp[wid][20 * (l15 + 15) + qr0];  // + fn*320, b64
    unsigned short* PsW = &Elp[wid][qr0 * 68 + l15];               // + fn*16 + r*68
    const unsigned short* PsR = &Elp[wid][l15 * 68];               // + kc*32 + l16*8

    s16x8 ones;
#pragma unroll
    for (int t = 0; t < 8; ++t) ones[t] = (short)0x3F80;  // bf16 1.0

    for (int h = 0; h < 2; ++h) {
        int it8 = h ? 15 - bx2 : bx2;
        int i0 = it8 * 64;
        int njt = it8 + 17;
        int jjb = 960 - i0;  // band base: jj = jjb + j0 + rbase + bcol

        // Q fragments (pre-scaled by SC)
        s16x8 aq[2], aqr[2];
        {
            int qrow = i0 + wid * 16 + l15;
#pragma unroll
            for (int kc = 0; kc < 2; ++kc) {
                s16x8 qv = *(const s16x8*)(qb + bq + (size_t)qrow * 64 + kc * 32 + l16 * 8);
                s16x8 q1, q2;
#pragma unroll
                for (int t = 0; t < 8; ++t) {
                    float ff = bf2f((unsigned short)qv[t]);
                    float rw = r_w_bias[n * 64 + kc * 32 + l16 * 8 + t];
                    q1[t] = (short)f2bf(ff * SC);
                    q2[t] = (short)f2bf((ff + rw) * SC);
                }
                aq[kc] = q1;
                aqr[kc] = q2;
            }
        }

        float m_[4];
        f32x4 accO[4], accL;
#pragma unroll
        for (int r = 0; r < 4; ++r) m_[r] = -3.0e38f;
#pragma unroll
        for (int ff = 0; ff < 4; ++ff) accO[ff] = f32x4{0.f, 0.f, 0.f, 0.f};
        accL = f32x4{0.f, 0.f, 0.f, 0.f};

        // ---- prologue: K/V tile 0, R band rows [0,128), rbs ----
#pragma unroll
        for (int q = 0; q < 2; ++q) {
            int s = wid * 2 + q;
            int row = s * 8 + lrow;
            gload16(kb + bk + (size_t)row * 64 + scolE, (char*)Ks[0] + s * 1024);
            gload16(vt + bk + (size_t)row * 2048 + scolE, (char*)Vs[0] + s * 1024);
        }
#pragma unroll
        for (int q = 0; q < 4; ++q) {
            int s = wid * 4 + q;
            int jju = jjb + s * 8 + lrow;  // <= 1087, no clamp needed
            gload16(rb + (size_t)n * 131072 + (size_t)jju * 64 + scolE,
                    (char*)Rs + (s * 8) * 128);
        }
        if (tid < 128) {
            int jju = jjb + tid;
            rbs[tid] = SC * rbt[(size_t)n * 2048 + jju];
        }
        __syncthreads();

        int cur = 0, rsb = 0;
        for (int jt = 0; jt < njt; ++jt) {
            int j0 = jt * 64;
            int jjc = jjb + j0;
            bool pf = (jt + 1 < njt);

            // E = q . R_window^T (16x80/wave) -> skewed El, rbias+mask folded
            __builtin_amdgcn_s_setprio(1);
#pragma unroll
            for (int fe = 0; fe < 5; ++fe) {
                int row = rsb + rbase + fe * 16 + l15;
                if (row >= 192) row -= 192;
                f32x4 e = f32x4{0.f, 0.f, 0.f, 0.f};
                e = mfma16(aq[0], ldfrag(Rs, row, l16 * 16), e);
                e = mfma16(aq[1], ldfrag(Rs, row, 64 + l16 * 16), e);
                float rbv = rbs[row];
                uint32_t p01 = cvtpk(e[0] + rbv, e[1] + rbv);
                uint32_t p23 = cvtpk(e[2] + rbv, e[3] + rbv);
                ElW[fe * 320] = (unsigned short)p01;
                ElW[fe * 320 + 21] = (unsigned short)(p01 >> 16);
                ElW[fe * 320 + 42] = (unsigned short)p23;
                ElW[fe * 320 + 63] = (unsigned short)(p23 >> 16);
            }
            // AC = (q + r_w_bias) . K^T
            f32x4 sAC[4];
#pragma unroll
            for (int fn = 0; fn < 4; ++fn) {
                f32x4 a = f32x4{0.f, 0.f, 0.f, 0.f};
#pragma unroll
                for (int kc = 0; kc < 2; ++kc)
                    a = mfma16(aqr[kc], ldfrag(Ks[cur], fn * 16 + l15, kc * 64 + l16 * 16), a);
                sAC[fn] = a;
            }
            __builtin_amdgcn_s_setprio(0);

            // prefetch issue (flies under softmax + PV + barrier)
            if (pf) {
                int j0n = j0 + 64;
#pragma unroll
                for (int q = 0; q < 2; ++q) {
                    int s = wid * 2 + q;
                    int row = s * 8 + lrow;
                    gload16(kb + bk + (size_t)(j0n + row) * 64 + scolE,
                            (char*)Ks[cur ^ 1] + s * 1024);
                    gload16(vt + bk + (size_t)row * 2048 + j0n + scolE,
                            (char*)Vs[cur ^ 1] + s * 1024);
                }
#pragma unroll
                for (int q = 0; q < 2; ++q) {
                    int s = wid * 2 + q;
                    int w = rsb + 128 + s * 8;
                    if (w >= 192) w -= 192;
                    int jju = jjc + 128 + s * 8 + lrow;
                    int jja = jju > 2047 ? 2047 : jju;  // clamp source only
                    gload16(rb + (size_t)n * 131072 + (size_t)jja * 64 + scolE,
                            (char*)Rs + w * 128);
                }
                if (tid < 64) {
                    int w = rsb + 128 + tid;
                    if (w >= 192) w -= 192;
                    int jju = jjc + 128 + tid;
                    rbs[w] = (jju <= 2047) ? SC * rbt[(size_t)n * 2048 + jju] : -1.0e30f;
                }
            }

            // softmax: scores via 4x b64 diagonal reads; defer-max THR=8
            float pe[4][4];
            float lmax[4] = {-3.0e38f, -3.0e38f, -3.0e38f, -3.0e38f};
#pragma unroll
            for (int fn = 0; fn < 4; ++fn) {
                uint2 ev = *(const uint2*)(ElR + fn * 320);
                pe[fn][0] = sAC[fn][0] + bfu_lo(ev.x);
                pe[fn][1] = sAC[fn][1] + bfu_hi(ev.x);
                pe[fn][2] = sAC[fn][2] + bfu_lo(ev.y);
                pe[fn][3] = sAC[fn][3] + bfu_hi(ev.y);
#pragma unroll
                for (int r = 0; r < 4; ++r) lmax[r] = fmaxf(lmax[r], pe[fn][r]);
            }
            bool need = (lmax[0] > m_[0] + 8.f) | (lmax[1] > m_[1] + 8.f) |
                        (lmax[2] > m_[2] + 8.f) | (lmax[3] > m_[3] + 8.f);
            if (__any(need)) {
#pragma unroll
                for (int msk = 1; msk <= 8; msk <<= 1)
#pragma unroll
                    for (int r = 0; r < 4; ++r)
                        lmax[r] = fmaxf(lmax[r], __shfl_xor(lmax[r], msk, 64));
#pragma unroll
                for (int r = 0; r < 4; ++r) {
                    float mn = fmaxf(m_[r], lmax[r]);
                    float alpha = __builtin_exp2f(m_[r] - mn);
                    m_[r] = mn;
                    accL[r] *= alpha;
#pragma unroll
                    for (int ff = 0; ff < 4; ++ff) accO[ff][r] *= alpha;
                }
            }
            // all El reads above complete before these aliased Ps writes
#pragma unroll
            for (int fn = 0; fn < 4; ++fn) {
                float e0 = __builtin_exp2f(pe[fn][0] - m_[0]);
                float e1 = __builtin_exp2f(pe[fn][1] - m_[1]);
                float e2 = __builtin_exp2f(pe[fn][2] - m_[2]);
                float e3 = __builtin_exp2f(pe[fn][3] - m_[3]);
                uint32_t a = cvtpk(e0, e1);
                uint32_t c = cvtpk(e2, e3);
                PsW[fn * 16] = (unsigned short)a;
                PsW[fn * 16 + 68] = (unsigned short)(a >> 16);
                PsW[fn * 16 + 136] = (unsigned short)c;
                PsW[fn * 16 + 204] = (unsigned short)(c >> 16);
            }

            // PV (+ row-sum via ones-MFMA); Ps rows 8B-aligned -> 2x b64
            __builtin_amdgcn_s_setprio(1);
#pragma unroll
            for (int kc = 0; kc < 2; ++kc) {
                const uint2* pp = (const uint2*)(PsR + kc * 32 + l16 * 8);
                union { uint2 u2[2]; s16x8 v; } uu;
                uu.u2[0] = pp[0];
                uu.u2[1] = pp[1];
                s16x8 pa = uu.v;
                accL = mfma16(pa, ones, accL);
#pragma unroll
                for (int fd = 0; fd < 4; ++fd)
                    accO[fd] = mfma16(pa, ldfrag(Vs[cur], fd * 16 + l15, kc * 64 + l16 * 16),
                                      accO[fd]);
            }
            __builtin_amdgcn_s_setprio(0);

            __syncthreads();  // single barrier: drains prefetch, publishes all buffers
            cur ^= 1;
            rsb += 64;
            if (rsb == 192) rsb = 0;
        }

        // write attn_vec row-normalized, bf16, layout [i*4+b][n*64+d]
#pragma unroll
        for (int r = 0; r < 4; ++r) {
            float inv = 1.f / accL[r];
            int ig = i0 + wid * 16 + qr0 + r;
#pragma unroll
            for (int fd = 0; fd < 4; ++fd)
                av[((size_t)ig * 4 + b) * 1024 + n * 64 + fd * 16 + l15] = f2bf(accO[fd][r] * inv);
        }
    }
}

// ---------------------------------------------------------------- layernorm (in-place on d_out)
__global__ __launch_bounds__(256) void k_ln(float* __restrict__ y, const float* __restrict__ g,
                                            const float* __restrict__ bta) {
    int row = blockIdx.x, tid = threadIdx.x;
    int lane = tid & 63, wid = tid >> 6;
    float4 v = ((const float4*)(y + (size_t)row * 1024))[tid];
    float s = v.x + v.y + v.z + v.w;
    float sq = v.x * v.x + v.y * v.y + v.z * v.z + v.w * v.w;
#pragma unroll
    for (int msk = 1; msk <= 32; msk <<= 1) {
        s += __shfl_xor(s, msk, 64);
        sq += __shfl_xor(sq, msk, 64);
    }
    __shared__ float red[2][4];
    if (lane == 0) { red[0][wid] = s; red[1][wid] = sq; }
    __syncthreads();
    s = red[0][0] + red[0][1] + red[0][2] + red[0][3];
    sq = red[1][0] + red[1][1] + red[1][2] + red[1][3];
    float mu = s * (1.f / 1024.f);
    float var = sq * (1.f / 1024.f) - mu * mu;
    float rs = rsqrtf(var + 1e-5f);
    float4 gv = ((const float4*)g)[tid];
    float4 bv = ((const float4*)bta)[tid];
    float4 o;
    o.x = (v.x - mu) * rs * gv.x + bv.x;
    o.y = (v.y - mu) * rs * gv.y + bv.y;
    o.z = (v.z - mu) * rs * gv.z + bv.z;
    o.w = (v.w - mu) * rs * gv.w + bv.w;
    ((float4*)(y + (size_t)row * 1024))[tid] = o;
}

// ---------------------------------------------------------------- launch
extern "C" void kernel_launch(void* const* d_in, const int* in_sizes, int n_in,
                              void* d_out, int out_size, void* d_ws, size_t ws_size,
                              hipStream_t stream) {
    const float* w      = (const float*)d_in[0];
    const float* mems   = (const float*)d_in[1];
    const float* r_emb  = (const float*)d_in[2];
    const float* r_wb   = (const float*)d_in[3];
    const float* r_bias = (const float*)d_in[4];
    const float* Wqkv   = (const float*)d_in[5];
    const float* Wo     = (const float*)d_in[6];
    const float* ln_g   = (const float*)d_in[7];
    const float* ln_b   = (const float*)d_in[8];
    float* out = (float*)d_out;

    char* p = (char*)d_ws;
    auto alloc = [&](size_t bytes) {
        char* q = p;
        p += (bytes + 255) & ~(size_t)255;
        return q;
    };
    unsigned short* catb  = (unsigned short*)alloc(8192ull * 1024 * 2);      // 16 MB
    unsigned short* wqkvT = (unsigned short*)alloc(3072ull * 1024 * 2);      // 6 MB
    unsigned short* woT   = (unsigned short*)alloc(1024ull * 1024 * 2);      // 2 MB
    unsigned short* rb    = (unsigned short*)alloc(16ull * 2048 * 64 * 2);   // 4 MB
    float*          rbt   = (float*)alloc(16ull * 2048 * 4);                 // 128 KB
    unsigned short* qbuf  = (unsigned short*)alloc(64ull * 1024 * 64 * 2);   // 8 MB
    unsigned short* kbuf  = (unsigned short*)alloc(64ull * 2048 * 64 * 2);   // 16 MB
    unsigned short* vtb   = (unsigned short*)alloc(64ull * 2048 * 64 * 2);   // 16 MB (transposed V)
    unsigned short* av    = (unsigned short*)alloc(4096ull * 1024 * 2);      // 8 MB

    k_prep_all<<<5632, 256, 0, stream>>>(mems, w, r_emb, r_bias, Wqkv, Wo,
                                         catb, wqkvT, woT, rb, rbt);

    // GEMM1: 1280 blocks, dead-tile remap; V written transposed in-epilogue
    k_gemm_qkv<<<1280, 256, 0, stream>>>(catb, wqkvT, qbuf, kbuf, vtb);
    k_attn<<<dim3(8, 64), 256, 0, stream>>>(qbuf, kbuf, vtb, rb, rbt, r_wb, av);
    k_gemm_out<<<dim3(8, 64), 256, 0, stream>>>(av, woT, w, out);
    k_ln<<<4096, 256, 0, stream>>>(out, ln_g, ln_b);
}